// Round 7
// baseline (769.473 us; speedup 1.0000x reference)
//
#include <hip/hip_runtime.h>
#include <hip/hip_bf16.h>
#include <math.h>

// ---- problem dims ----
#define B_      2
#define T_      4096
#define E_      512
#define H_      8
#define DH_     64
#define DEPTH_  4
#define NHASH_  4
#define BUCKET_ 64
#define NB_     64
#define NB2_    32
#define C_      (NHASH_*NB_)      // 256 chunks per bh
#define BH_     (B_*H_)           // 16
#define NT_     (NHASH_*T_)       // 16384
#define FF_     2048
#define NCLASS_ 10
#define MASKV   (-1e9f)
#define SELFV   (-5e4f)

typedef __attribute__((ext_vector_type(8))) short short8;   // 8 bf16 = 4 VGPR
typedef __attribute__((ext_vector_type(4))) float f32x4;

__device__ __forceinline__ void gload_lds16(const void* g, void* l) {
    __builtin_amdgcn_global_load_lds(
        (const __attribute__((address_space(1))) void*)g,
        (__attribute__((address_space(3))) void*)l,
        16, 0, 0);
}

__device__ __forceinline__ unsigned pk2(float a, float b) {
    __hip_bfloat16 ha = __float2bfloat16(a), hb = __float2bfloat16(b);
    unsigned short ua = *(unsigned short*)&ha, ub = *(unsigned short*)&hb;
    return (unsigned)ua | ((unsigned)ub << 16);
}

// ---------------- embed: h = tok_emb[x] + pos_emb ----------------
__global__ __launch_bounds__(128) void k_embed(const int* __restrict__ x, const float* __restrict__ tok,
                                               const float* __restrict__ pos, float* __restrict__ x1,
                                               float* __restrict__ x2)
{
    int bt = blockIdx.x;
    int t  = bt & (T_ - 1);
    int id = x[bt];
    float4 tv = ((const float4*)(tok + (size_t)id * E_))[threadIdx.x];
    float4 pv = ((const float4*)(pos + (size_t)t * E_))[threadIdx.x];
    float4 hv = make_float4(tv.x + pv.x, tv.y + pv.y, tv.z + pv.z, tv.w + pv.w);
    ((float4*)(x1 + (size_t)bt * E_))[threadIdx.x] = hv;
    ((float4*)(x2 + (size_t)bt * E_))[threadIdx.x] = hv;
}

// ---------------- layernorm over E=512 -> bf16 (hi) [+ bf16 residual (lo)] ----------------
template<bool LO>
__global__ __launch_bounds__(128) void k_ln(const float* __restrict__ in, const float* __restrict__ g,
                                            const float* __restrict__ b, __hip_bfloat16* __restrict__ out,
                                            __hip_bfloat16* __restrict__ outlo)
{
    int row = blockIdx.x, tid = threadIdx.x;
    float4 v = ((const float4*)(in + (size_t)row * E_))[tid];
    float s = v.x + v.y + v.z + v.w;
    float q = v.x * v.x + v.y * v.y + v.z * v.z + v.w * v.w;
#pragma unroll
    for (int d = 1; d < 64; d <<= 1) { s += __shfl_xor(s, d); q += __shfl_xor(q, d); }
    __shared__ float red[4];
    int w = tid >> 6;
    if ((tid & 63) == 0) { red[w * 2] = s; red[w * 2 + 1] = q; }
    __syncthreads();
    s = red[0] + red[2]; q = red[1] + red[3];
    float mean = s * (1.0f / E_);
    float var  = q * (1.0f / E_) - mean * mean;
    float rstd = rsqrtf(var + 1e-5f);
    float4 gv = ((const float4*)g)[tid];
    float4 bv = ((const float4*)b)[tid];
    float o0 = (v.x - mean) * rstd * gv.x + bv.x;
    float o1 = (v.y - mean) * rstd * gv.y + bv.y;
    float o2 = (v.z - mean) * rstd * gv.z + bv.z;
    float o3 = (v.w - mean) * rstd * gv.w + bv.w;
    __hip_bfloat16* op = out + (size_t)row * E_ + tid * 4;
    __hip_bfloat16 h0 = __float2bfloat16(o0), h1 = __float2bfloat16(o1);
    __hip_bfloat16 h2 = __float2bfloat16(o2), h3 = __float2bfloat16(o3);
    op[0] = h0; op[1] = h1; op[2] = h2; op[3] = h3;
    if (LO) {
        __hip_bfloat16* lp = outlo + (size_t)row * E_ + tid * 4;
        lp[0] = __float2bfloat16(o0 - __bfloat162float(h0));
        lp[1] = __float2bfloat16(o1 - __bfloat162float(h1));
        lp[2] = __float2bfloat16(o2 - __bfloat162float(h2));
        lp[3] = __float2bfloat16(o3 - __bfloat162float(h3));
    }
}

// ------- weight transpose + bf16 cast (all 4 layers batched via blockIdx.z) -------
template<bool SPLIT>
__global__ __launch_bounds__(256) void k_wprep(const float* __restrict__ W, __hip_bfloat16* __restrict__ WT,
                                               __hip_bfloat16* __restrict__ WTlo, int K, int N)
{
    __shared__ float tile[32][33];
    size_t lofs = (size_t)blockIdx.z * K * N;
    W  += lofs;
    WT += lofs;
    if (SPLIT) WTlo += lofs;
    int n0 = blockIdx.x * 32, k0 = blockIdx.y * 32;
    int tx = threadIdx.x & 31, ty = threadIdx.x >> 5;
#pragma unroll
    for (int i = 0; i < 4; ++i) {
        int k = ty + i * 8;
        tile[k][tx] = W[(size_t)(k0 + k) * N + n0 + tx];
    }
    __syncthreads();
#pragma unroll
    for (int i = 0; i < 4; ++i) {
        int n = ty + i * 8;
        float v = tile[tx][n];
        __hip_bfloat16 hv = __float2bfloat16(v);
        WT[(size_t)(n0 + n) * K + k0 + tx] = hv;
        if (SPLIT)
            WTlo[(size_t)(n0 + n) * K + k0 + tx] = __float2bfloat16(v - __bfloat162float(hv));
    }
}

// ---- rot prep (4 layers batched: blockIdx.x = layer) ----
__global__ __launch_bounds__(256) void k_rotprep(const float* __restrict__ rot,
                                                 __hip_bfloat16* __restrict__ rhs,
                                                 __hip_bfloat16* __restrict__ rls)
{
    int d = blockIdx.x;
    rot += (size_t)d * 64 * 128;
    rhs += (size_t)d * 8192;
    rls += (size_t)d * 8192;
    int tid = threadIdx.x;
    for (int idx = tid; idx < 128 * 64; idx += 256) {
        int row = idx >> 6, f = idx & 63;
        float v = rot[(size_t)f * 128 + row];
        __hip_bfloat16 hv = __float2bfloat16(v);
        __hip_bfloat16 lv = __float2bfloat16(v - __bfloat162float(hv));
        int b = f >> 3;
        int off = row * 64 + (((b ^ (row & 7)) << 3) | (f & 7));
        rhs[off] = hv;
        rls[off] = lv;
    }
}

// fast exact-GELU: erf via Abramowitz-Stegun 7.1.26 (|eps| <= 1.5e-7), one v_exp + v_rcp
__device__ __forceinline__ float geluf(float x) {
    float ax = fabsf(x) * 0.70710678118654752f;
    float t  = __builtin_amdgcn_rcpf(1.0f + 0.3275911f * ax);
    float poly = t * (0.254829592f + t * (-0.284496736f + t * (1.421413741f +
                 t * (-1.453152027f + t * 1.061405429f))));
    float e = __expf(-ax * ax);
    float erfax = 1.0f - poly * e;
    float erfx = copysignf(erfax, x);
    return 0.5f * x * (1.0f + erfx);
}

// ---------------- bf16 MFMA GEMM: 2-phase dbuf, BK=64, XCD swizzle ----
// OUTK: 1 = f32 ACC store, 2 = bf16 GELU store, 3 = bf16 store to head-gathered vh layout.
template<int OUTK, int BIAS, int TM>
__global__ __launch_bounds__(256) void k_mgemm(const __hip_bfloat16* __restrict__ A,
                                               const __hip_bfloat16* __restrict__ WT,
                                               const float* __restrict__ bias, void* __restrict__ Cout,
                                               int N, int K, int nbnShift)
{
    constexpr int MF = TM / 32;               // A fragments / wave (and A gloads / thread)
    constexpr int ABYTES = TM * 128;          // per-buffer A bytes (TM rows x 64 k x 2B)
    __shared__ __align__(16) char smem[2 * ABYTES + 32768];
    char* BbBase = smem + 2 * ABYTES;

    int tid = threadIdx.x;
    int lane = tid & 63, wv = tid >> 6, w = wv;
    int nwg = gridDim.x;
    int bid = blockIdx.x;
    int swz = (bid & 7) * (nwg >> 3) + (bid >> 3);
    int nmask = (1 << nbnShift) - 1;
    int m0 = (swz >> nbnShift) * TM, n0 = (swz & nmask) * 128;
    int wm = (w >> 1) * (TM / 2), wn = (w & 1) * 64;

    // staging sources: dest slot d = (wv + g*4)*64 + lane (wave-contiguous); row = d>>3, slot = d&7
    const __hip_bfloat16* aSg[MF];
    int aDd[MF];
#pragma unroll
    for (int g = 0; g < MF; ++g) {
        int d = (wv + g * 4) * 64 + lane;
        int row = d >> 3, slot = d & 7;
        int c = (slot - ((row >> 1) & 7)) & 7;
        aSg[g] = A + (size_t)(m0 + row) * K + c * 8;
        aDd[g] = d * 16;
    }
    const __hip_bfloat16* bSg[4];
    int bDd[4];
#pragma unroll
    for (int g = 0; g < 4; ++g) {
        int d = (wv + g * 4) * 64 + lane;
        int row = d >> 3, slot = d & 7;
        int c = (slot - ((row >> 1) & 7)) & 7;
        bSg[g] = WT + (size_t)(n0 + row) * K + c * 8;
        bDd[g] = d * 16;
    }

    int cch = lane >> 4;
    int aoff[MF][2], boff[4][2];
#pragma unroll
    for (int f = 0; f < MF; ++f) {
        int ar = wm + f * 16 + (lane & 15);
        int rot = (ar >> 1) & 7;
#pragma unroll
        for (int h = 0; h < 2; ++h)
            aoff[f][h] = ar * 128 + (((h * 4 + cch) + rot) & 7) * 16;
    }
#pragma unroll
    for (int f = 0; f < 4; ++f) {
        int br = wn + f * 16 + (lane & 15);
        int rot = (br >> 1) & 7;
#pragma unroll
        for (int h = 0; h < 2; ++h)
            boff[f][h] = br * 128 + (((h * 4 + cch) + rot) & 7) * 16;
    }

    f32x4 acc[MF][4];
#pragma unroll
    for (int i = 0; i < MF; ++i)
#pragma unroll
        for (int j = 0; j < 4; ++j) acc[i][j] = (f32x4){0.f, 0.f, 0.f, 0.f};

    const int NS = K >> 6;
    {
#pragma unroll
        for (int g = 0; g < MF; ++g) gload_lds16(aSg[g], smem + aDd[g]);
#pragma unroll
        for (int g = 0; g < 4; ++g)  gload_lds16(bSg[g], BbBase + bDd[g]);
    }
    __syncthreads();
    for (int s = 0; s < NS; ++s) {
        int cur = s & 1;
        if (s + 1 < NS) {
            int nb = cur ^ 1;
            int kk = (s + 1) * 64;
            char* Abn = smem + nb * ABYTES;
            char* Bbn = BbBase + nb * 16384;
#pragma unroll
            for (int g = 0; g < MF; ++g) gload_lds16(aSg[g] + kk, Abn + aDd[g]);
#pragma unroll
            for (int g = 0; g < 4; ++g)  gload_lds16(bSg[g] + kk, Bbn + bDd[g]);
        }
        const char* Ab = smem + cur * ABYTES;
        const char* Bb = BbBase + cur * 16384;
#pragma unroll
        for (int h = 0; h < 2; ++h) {
            short8 af[MF], bfr[4];
#pragma unroll
            for (int f = 0; f < MF; ++f) af[f] = *(const short8*)(Ab + aoff[f][h]);
#pragma unroll
            for (int f = 0; f < 4; ++f)  bfr[f] = *(const short8*)(Bb + boff[f][h]);
#pragma unroll
            for (int i = 0; i < MF; ++i)
#pragma unroll
                for (int j = 0; j < 4; ++j)
                    acc[i][j] = __builtin_amdgcn_mfma_f32_16x16x32_bf16(af[i], bfr[j], acc[i][j], 0, 0, 0);
        }
        __syncthreads();
    }

    int g = lane >> 4;
    if (OUTK == 2 || OUTK == 3) {
        unsigned short* Ot = (unsigned short*)smem;
#pragma unroll
        for (int i = 0; i < MF; ++i) {
#pragma unroll
            for (int j = 0; j < 4; ++j) {
                int col = wn + j * 16 + (lane & 15);
                float bv = BIAS ? bias[n0 + col] : 0.f;
#pragma unroll
                for (int q = 0; q < 4; ++q) {
                    int row = wm + i * 16 + g * 4 + q;
                    float vv = acc[i][j][q] + bv;
                    if (OUTK == 2) vv = geluf(vv);
                    __hip_bfloat16 hv = __float2bfloat16(vv);
                    Ot[row * 128 + (((col >> 3) ^ (row & 7)) << 3) + (col & 7)] = *(unsigned short*)&hv;
                }
            }
        }
        __syncthreads();
#pragma unroll
        for (int u = 0; u < TM / 16; ++u) {
            int f = u * 256 + tid;
            int row = f >> 4, cblk = f & 15;
            uint4 v = *(const uint4*)(Ot + row * 128 + ((cblk ^ (row & 7)) << 3));
            if (OUTK == 2) {
                *(uint4*)((__hip_bfloat16*)Cout + (size_t)(m0 + row) * N + n0 + cblk * 8) = v;
            } else {
                int mrow = m0 + row;
                int t = mrow & (T_ - 1), bI = mrow >> 12;
                int col = n0 + cblk * 8;
                int h = col >> 6, fin = col & 63;
                *(uint4*)((__hip_bfloat16*)Cout + ((size_t)(bI * H_ + h) * T_ + t) * 64 + fin) = v;
            }
        }
    } else {
        float* Ot = (float*)smem;
        float* Cb = (float*)Cout;
#pragma unroll
        for (int i = 0; i < MF; ++i) {
#pragma unroll
            for (int j = 0; j < 4; ++j) {
                int col = wn + j * 16 + (lane & 15);
#pragma unroll
                for (int q = 0; q < 4; ++q) {
                    int row = wm + i * 16 + g * 4 + q;
                    Ot[row * 128 + (((col >> 2) ^ (row & 7)) << 2) + (col & 3)] = acc[i][j][q];
                }
            }
        }
        __syncthreads();
#pragma unroll
        for (int u = 0; u < 8; ++u) {
            int f = u * 256 + tid;
            int row = f >> 5, c4 = f & 31;
            float4 v = *(const float4*)(Ot + row * 128 + ((c4 ^ (row & 7)) << 2));
            if (BIAS) {
                float4 bv = *(const float4*)(bias + n0 + c4 * 4);
                v.x += bv.x; v.y += bv.y; v.z += bv.z; v.w += bv.w;
            }
            float* cp = Cb + (size_t)(m0 + row) * N + n0 + c4 * 4;
            float4 old = *(const float4*)cp;
            v.x += old.x; v.y += old.y; v.z += old.z; v.w += old.w;
            *(float4*)cp = v;
        }
    }
}

// ---------------- fused split-bf16 QK GEMM: BK=64, 64x64 tiles, rotation-swizzled LDS ---------
// qk = Ah*Bh + Ah*Bl + Al*Bh ; accumulation order per 32-k chunk identical to prior kernel.
__global__ __launch_bounds__(256) void k_qk64(const __hip_bfloat16* __restrict__ Ah,
                                              const __hip_bfloat16* __restrict__ Al,
                                              const __hip_bfloat16* __restrict__ Bh,
                                              const __hip_bfloat16* __restrict__ Bl,
                                              float* __restrict__ Cout)
{
    const int N = 512, K = 512;
    __shared__ __align__(16) char smem[65536];   // 2 bufs x 32KB (Ah|Al|Bh|Bl 8KB each)
    int tid = threadIdx.x;
    int lane = tid & 63, wv = tid >> 6;
    int nwg = gridDim.x;                          // 1024
    int bid = blockIdx.x;
    int swz = (bid & 7) * (nwg >> 3) + (bid >> 3);
    int m0 = (swz >> 3) * 64, n0 = (swz & 7) * 64;
    int wm = (wv >> 1) * 32, wn = (wv & 1) * 32;

    // staging: per array 512 slots of 16B; dest d = (wv + g*4)*64 + lane; row=d>>3, slot=d&7
    const __hip_bfloat16* sAh[2]; const __hip_bfloat16* sAl[2];
    const __hip_bfloat16* sBh[2]; const __hip_bfloat16* sBl[2];
    int dOf[2];
#pragma unroll
    for (int g = 0; g < 2; ++g) {
        int d = (wv + g * 4) * 64 + lane;
        int row = d >> 3, slot = d & 7;
        int c = (slot - ((row >> 1) & 7)) & 7;
        dOf[g] = d * 16;
        sAh[g] = Ah + (size_t)(m0 + row) * K + c * 8;
        sAl[g] = Al + (size_t)(m0 + row) * K + c * 8;
        sBh[g] = Bh + (size_t)(n0 + row) * K + c * 8;
        sBl[g] = Bl + (size_t)(n0 + row) * K + c * 8;
    }

    int cch = lane >> 4;
    int aoff[2][2], boff[2][2];     // [frag][half]
#pragma unroll
    for (int f = 0; f < 2; ++f) {
        int ar = wm + f * 16 + (lane & 15);
        int rta = (ar >> 1) & 7;
        int br = wn + f * 16 + (lane & 15);
        int rtb = (br >> 1) & 7;
#pragma unroll
        for (int h = 0; h < 2; ++h) {
            aoff[f][h] = ar * 128 + (((h * 4 + cch) + rta) & 7) * 16;
            boff[f][h] = br * 128 + (((h * 4 + cch) + rtb) & 7) * 16;
        }
    }

    f32x4 acc[2][2];
#pragma unroll
    for (int i = 0; i < 2; ++i)
#pragma unroll
        for (int j = 0; j < 2; ++j) acc[i][j] = (f32x4){0.f, 0.f, 0.f, 0.f};

#define QK_STG(buf, kk)                                              \
    { char* bb = smem + (buf) * 32768;                               \
      _Pragma("unroll")                                              \
      for (int g = 0; g < 2; ++g) {                                  \
          gload_lds16(sAh[g] + (kk), bb + dOf[g]);                   \
          gload_lds16(sAl[g] + (kk), bb + 8192  + dOf[g]);           \
          gload_lds16(sBh[g] + (kk), bb + 16384 + dOf[g]);           \
          gload_lds16(sBl[g] + (kk), bb + 24576 + dOf[g]);           \
      } }

    QK_STG(0, 0)
    __syncthreads();
    const int NS = K >> 6;    // 8
    for (int s = 0; s < NS; ++s) {
        int cur = s & 1;
        if (s + 1 < NS) QK_STG(cur ^ 1, (s + 1) * 64)
        const char* bb = smem + cur * 32768;
#pragma unroll
        for (int h = 0; h < 2; ++h) {
            short8 afh[2], afl[2], bfh[2], bfl[2];
#pragma unroll
            for (int f = 0; f < 2; ++f) {
                afh[f] = *(const short8*)(bb + aoff[f][h]);
                afl[f] = *(const short8*)(bb + 8192  + aoff[f][h]);
                bfh[f] = *(const short8*)(bb + 16384 + boff[f][h]);
                bfl[f] = *(const short8*)(bb + 24576 + boff[f][h]);
            }
#pragma unroll
            for (int i = 0; i < 2; ++i)
#pragma unroll
                for (int j = 0; j < 2; ++j) {
                    acc[i][j] = __builtin_amdgcn_mfma_f32_16x16x32_bf16(afh[i], bfh[j], acc[i][j], 0, 0, 0);
                    acc[i][j] = __builtin_amdgcn_mfma_f32_16x16x32_bf16(afh[i], bfl[j], acc[i][j], 0, 0, 0);
                    acc[i][j] = __builtin_amdgcn_mfma_f32_16x16x32_bf16(afl[i], bfh[j], acc[i][j], 0, 0, 0);
                }
        }
        __syncthreads();
    }
#undef QK_STG

    int g = lane >> 4;
    float* Ot = (float*)smem;
#pragma unroll
    for (int i = 0; i < 2; ++i)
#pragma unroll
        for (int j = 0; j < 2; ++j) {
            int col = wn + j * 16 + (lane & 15);
#pragma unroll
            for (int q = 0; q < 4; ++q) {
                int row = wm + i * 16 + g * 4 + q;
                Ot[row * 64 + (((col >> 2) ^ (row & 7)) << 2) + (col & 3)] = acc[i][j][q];
            }
        }
    __syncthreads();
#pragma unroll
    for (int u = 0; u < 4; ++u) {
        int f = u * 256 + tid;
        int row = f >> 4, c4 = f & 15;
        float4 v = *(const float4*)(Ot + row * 64 + ((c4 ^ (row & 7)) << 2));
        *(float4*)(Cout + (size_t)(m0 + row) * N + n0 + c4 * 4) = v;
    }
}

// ---------------- MFMA LSH hashing: 128 tokens/block, rotated = mfma(rot, q), + q/k' emission --
__global__ __launch_bounds__(256) void k_hash(const float* __restrict__ qk,
                                              const __hip_bfloat16* __restrict__ rhs,
                                              const __hip_bfloat16* __restrict__ rls,
                                              unsigned char* __restrict__ bkt,
                                              __hip_bfloat16* __restrict__ qh,
                                              __hip_bfloat16* __restrict__ kh)
{
    __shared__ __align__(16) char smem[65536];
    char* RH = smem;            // [128][64] bf16 rot hi, XOR(row&7) swizzled (pre-swizzled image)
    char* RL = smem + 16384;    // rot lo
    char* QH = smem + 32768;    // [128][64] bf16 q hi, XOR(t&7)
    char* QL = smem + 49152;    // q lo
    int tid = threadIdx.x, lane = tid & 63, wv = tid >> 6;
    int bh = blockIdx.x, tc = blockIdx.y;       // grid (16, 32)
    int bI = bh >> 3, h = bh & 7;

#pragma unroll
    for (int it = 0; it < 4; ++it) {
        gload_lds16((const char*)rhs + it * 4096 + tid * 16, RH + it * 4096 + tid * 16);
        gload_lds16((const char*)rls + it * 4096 + tid * 16, RL + it * 4096 + tid * 16);
    }

    {
        int t = tid >> 1, half = tid & 1;
        int tg = tc * 128 + t;
        const float4* qsrc = (const float4*)(qk + ((size_t)(bI * T_ + tg)) * E_ + h * DH_ + half * 32);
        float4 q4[8];
        float n2 = 0.f;
#pragma unroll
        for (int j = 0; j < 8; ++j) {
            q4[j] = qsrc[j];
            n2 += q4[j].x * q4[j].x + q4[j].y * q4[j].y + q4[j].z * q4[j].z + q4[j].w * q4[j].w;
        }
        n2 += __shfl_xor(n2, 1);
        float sc = 0.125f / fmaxf(sqrtf(n2), 1e-12f);
        float qv[32];
#pragma unroll
        for (int j = 0; j < 8; ++j) {
            qv[4 * j] = q4[j].x; qv[4 * j + 1] = q4[j].y; qv[4 * j + 2] = q4[j].z; qv[4 * j + 3] = q4[j].w;
        }
        unsigned short hb[32], lb[32], kb[32];
#pragma unroll
        for (int j = 0; j < 32; ++j) {
            __hip_bfloat16 hv = __float2bfloat16(qv[j]);
            __hip_bfloat16 lv = __float2bfloat16(qv[j] - __bfloat162float(hv));
            __hip_bfloat16 kv = __float2bfloat16(qv[j] * sc);
            hb[j] = *(unsigned short*)&hv; lb[j] = *(unsigned short*)&lv; kb[j] = *(unsigned short*)&kv;
        }
        size_t ro = ((size_t)bh * T_ + tg) * 64 + half * 32;
        uint4* qdst = (uint4*)(qh + ro);
        uint4* kdst = (uint4*)(kh + ro);
#pragma unroll
        for (int j = 0; j < 4; ++j) {
            qdst[j] = *(uint4*)&hb[8 * j];
            kdst[j] = *(uint4*)&kb[8 * j];
        }
#pragma unroll
        for (int j = 0; j < 4; ++j) {
            int b = half * 4 + j;
            int xo = t * 128 + ((b ^ (t & 7)) << 4);
            *(uint4*)(QH + xo) = *(uint4*)&hb[8 * j];
            *(uint4*)(QL + xo) = *(uint4*)&lb[8 * j];
        }
    }
    __syncthreads();

#pragma unroll
    for (int sub = 0; sub < 2; ++sub) {
        int tl = wv * 32 + sub * 16 + (lane & 15);
        int g = lane >> 4;
        short8 qfh0 = *(const short8*)(QH + tl * 128 + ((g ^ (tl & 7)) << 4));
        short8 qfh1 = *(const short8*)(QH + tl * 128 + (((4 + g) ^ (tl & 7)) << 4));
        short8 qfl0 = *(const short8*)(QL + tl * 128 + ((g ^ (tl & 7)) << 4));
        short8 qfl1 = *(const short8*)(QL + tl * 128 + (((4 + g) ^ (tl & 7)) << 4));
        f32x4 sacc[8];
#pragma unroll
        for (int kt = 0; kt < 8; ++kt) sacc[kt] = (f32x4){0.f, 0.f, 0.f, 0.f};
#pragma unroll
        for (int kt = 0; kt < 8; ++kt) {
            int row = kt * 16 + (lane & 15);
            short8 rh0 = *(const short8*)(RH + row * 128 + ((g ^ (row & 7)) << 4));
            short8 rh1 = *(const short8*)(RH + row * 128 + (((4 + g) ^ (row & 7)) << 4));
            short8 rl0 = *(const short8*)(RL + row * 128 + ((g ^ (row & 7)) << 4));
            short8 rl1 = *(const short8*)(RL + row * 128 + (((4 + g) ^ (row & 7)) << 4));
            sacc[kt] = __builtin_amdgcn_mfma_f32_16x16x32_bf16(rh0, qfh0, sacc[kt], 0, 0, 0);
            sacc[kt] = __builtin_amdgcn_mfma_f32_16x16x32_bf16(rh1, qfh1, sacc[kt], 0, 0, 0);
            sacc[kt] = __builtin_amdgcn_mfma_f32_16x16x32_bf16(rl0, qfh0, sacc[kt], 0, 0, 0);
            sacc[kt] = __builtin_amdgcn_mfma_f32_16x16x32_bf16(rl1, qfh1, sacc[kt], 0, 0, 0);
            sacc[kt] = __builtin_amdgcn_mfma_f32_16x16x32_bf16(rh0, qfl0, sacc[kt], 0, 0, 0);
            sacc[kt] = __builtin_amdgcn_mfma_f32_16x16x32_bf16(rh1, qfl1, sacc[kt], 0, 0, 0);
        }
#pragma unroll
        for (int rd = 0; rd < 4; ++rd) {
            float bv = -3.0e38f; int bi = 0;
#pragma unroll
            for (int kp = 0; kp < 2; ++kp) {
#pragma unroll
                for (int rr = 0; rr < 4; ++rr) {
                    int i = kp * 16 + g * 4 + rr;
                    float v = sacc[rd * 2 + kp][rr];
                    if (v > bv) { bv = v; bi = i; }
                }
            }
#pragma unroll
            for (int kp = 0; kp < 2; ++kp) {
#pragma unroll
                for (int rr = 0; rr < 4; ++rr) {
                    int i = 32 + kp * 16 + g * 4 + rr;
                    float v = -sacc[rd * 2 + kp][rr];
                    if (v > bv) { bv = v; bi = i; }
                }
            }
#pragma unroll
            for (int dlt = 16; dlt <= 32; dlt <<= 1) {
                float ov = __shfl_xor(bv, dlt);
                int oi = __shfl_xor(bi, dlt);
                if (ov > bv || (ov == bv && oi < bi)) { bv = ov; bi = oi; }
            }
            if (g == 0)
                bkt[((size_t)(bh * NHASH_ + rd)) * T_ + tc * 128 + tl] = (unsigned char)bi;
        }
    }
}

// ---------------- parallel stable counting sort per (bh, round): 256 threads ----------------
__global__ __launch_bounds__(256) void k_sort(const unsigned char* __restrict__ bkt, int* __restrict__ st)
{
    __shared__ unsigned char bktL[T_];            // 4 KB
    __shared__ unsigned short hist[256][66];      // 33 KB, stride 66 breaks bank aliasing
    __shared__ unsigned short qtot[4][64];
    __shared__ int qbase[4][64];
    int tid = threadIdx.x;
    int bhr = blockIdx.x;
    const unsigned char* src = bkt + (size_t)bhr * T_;
    ((uint4*)bktL)[tid] = ((const uint4*)src)[tid];
    uint4* h4 = (uint4*)&hist[0][0];
    for (int j = tid; j < 2112; j += 256) h4[j] = make_uint4(0, 0, 0, 0);
    __syncthreads();
    int base = tid * 16;
#pragma unroll
    for (int i = 0; i < 16; ++i) hist[tid][bktL[base + i]]++;
    __syncthreads();
    int b = tid & 63, qd = tid >> 6;
    int t0 = qd * 64;
    unsigned run = 0;
#pragma unroll 8
    for (int tt = 0; tt < 64; ++tt) {
        unsigned v = hist[t0 + tt][b];
        hist[t0 + tt][b] = (unsigned short)run;
        run += v;
    }
    qtot[qd][b] = (unsigned short)run;
    __syncthreads();
    if (tid < 64) {
        int c0 = qtot[0][tid], c1 = qtot[1][tid], c2 = qtot[2][tid], c3 = qtot[3][tid];
        int tot = c0 + c1 + c2 + c3;
        int pre = tot;
#pragma unroll
        for (int d = 1; d < 64; d <<= 1) { int o = __shfl_up(pre, d); if (tid >= d) pre += o; }
        int startb = pre - tot;
        qbase[0][tid] = startb;
        qbase[1][tid] = startb + c0;
        qbase[2][tid] = startb + c0 + c1;
        qbase[3][tid] = startb + c0 + c1 + c2;
    }
    __syncthreads();
    int* dst = st + (size_t)bhr * T_;
#pragma unroll
    for (int i = 0; i < 16; ++i) {
        int bb = bktL[base + i];
        int off = hist[tid][bb]++;
        dst[qbase[qd][bb] + off] = base + i;
    }
}

// ---------------- MFMA chunked attention: one 4-wave block per (bh, chunk) ----------------
// o layout: [bh][t][rnd][64] bf16 ; lg layout: [bh][t][rnd] f32  (combine-coalesced)
// LDS 33.3KB: PbB aliases KbB (K dead after QK^T; barrier guards the overwrite) -> 4 blocks/CU.
__global__ __launch_bounds__(256, 4) void k_attn(const __hip_bfloat16* __restrict__ qh,
                                                 const __hip_bfloat16* __restrict__ kh,
                                                 const __hip_bfloat16* __restrict__ vh,
                                                 const int* __restrict__ st,
                                                 __hip_bfloat16* __restrict__ o,
                                                 float* __restrict__ lg)
{
    __shared__ __align__(16) char smem[33280];
    char* KbB = smem;                 // K tile (16KB); later aliased by PbB, then ObU
    char* VtB = smem + 16384;         // V^T tile (16KB)
    char* PbB = smem;                 // alias of KbB
    int*  kvt = (int*)(smem + 32768);
    unsigned short* ObU = (unsigned short*)smem;

    int tid = threadIdx.x;
    int lane = tid & 63;
    int g = lane >> 4;
    int wv = tid >> 6;
    int wq0 = wv * 16;

    int bid = blockIdx.x;
    int bh = ((bid & 7) << 1) | ((bid >> 3) & 1);
    int c  = bid >> 4;
    int rnd = c >> 6;
    int cp = (c + C_ - 1) & (C_ - 1);
    const size_t stB = (size_t)bh * NT_;

    if (tid < 128) {
        int cc = (tid < 64) ? c : cp;
        kvt[tid] = st[stB + (size_t)cc * 64 + (tid & 63)];
    }
    __syncthreads();

    {
        int k = tid >> 1, half = tid & 1;
        const uint4* src = (const uint4*)(kh + ((size_t)bh * T_ + kvt[k]) * 64 + half * 32);
#pragma unroll
        for (int j2 = 0; j2 < 4; ++j2) {
            uint4 a = src[j2];
            int blk = (half * 4 + j2) ^ (k & 7);
            *(uint4*)(KbB + k * 128 + blk * 16) = a;
        }
    }
    {
        int kp = tid & 63, dq = tid >> 6;
        const uint4* r0 = (const uint4*)(vh + ((size_t)bh * T_ + kvt[2 * kp]) * 64 + dq * 16);
        const uint4* r1 = (const uint4*)(vh + ((size_t)bh * T_ + kvt[2 * kp + 1]) * 64 + dq * 16);
        unsigned short va[16], vb2[16];
        *(uint4*)&va[0] = r0[0];  *(uint4*)&va[8] = r0[1];
        *(uint4*)&vb2[0] = r1[0]; *(uint4*)&vb2[8] = r1[1];
#pragma unroll
        for (int i = 0; i < 16; ++i) {
            int d = dq * 16 + i;
            unsigned wrd = (unsigned)va[i] | ((unsigned)vb2[i] << 16);
            *(unsigned*)(VtB + d * 256 + ((((kp >> 2) ^ i)) << 4) + ((kp & 3) << 2)) = wrd;
        }
    }
    int tq = kvt[wq0 + (lane & 15)];
    const __hip_bfloat16* qrow = qh + ((size_t)bh * T_ + tq) * 64;
    short8 qf0 = *(const short8*)(qrow + g * 8);
    short8 qf1 = *(const short8*)(qrow + 32 + g * 8);
    __syncthreads();

    f32x4 sacc[8];
#pragma unroll
    for (int kt = 0; kt < 8; ++kt) sacc[kt] = (f32x4){0.f, 0.f, 0.f, 0.f};
#pragma unroll
    for (int kt = 0; kt < 8; ++kt) {
        int row = kt * 16 + (lane & 15);
        short8 kf0 = *(const short8*)(KbB + row * 128 + (((g) ^ (row & 7)) << 4));
        short8 kf1 = *(const short8*)(KbB + row * 128 + (((4 + g) ^ (row & 7)) << 4));
        sacc[kt] = __builtin_amdgcn_mfma_f32_16x16x32_bf16(kf0, qf0, sacc[kt], 0, 0, 0);
        sacc[kt] = __builtin_amdgcn_mfma_f32_16x16x32_bf16(kf1, qf1, sacc[kt], 0, 0, 0);
    }

    float m = -3.0e38f;
#pragma unroll
    for (int kt = 0; kt < 8; ++kt) {
#pragma unroll
        for (int r = 0; r < 4; ++r) {
            int tk = kvt[kt * 16 + g * 4 + r];
            float dd = sacc[kt][r];
            dd = (tk > tq) ? MASKV : dd;
            dd = (tk == tq) ? SELFV : dd;
            sacc[kt][r] = dd;
            m = fmaxf(m, dd);
        }
    }
    m = fmaxf(m, __shfl_xor(m, 16));
    m = fmaxf(m, __shfl_xor(m, 32));
    __syncthreads();   // all KbB reads complete before P overwrites it (PbB alias)
    float ssum = 0.f;
#pragma unroll
    for (int kt = 0; kt < 8; ++kt) {
        float p0 = __expf(sacc[kt][0] - m);
        float p1 = __expf(sacc[kt][1] - m);
        float p2 = __expf(sacc[kt][2] - m);
        float p3 = __expf(sacc[kt][3] - m);
        ssum += (p0 + p1) + (p2 + p3);
        uint2 wrd = make_uint2(pk2(p0, p1), pk2(p2, p3));
        int blk = (kt * 2 + (g >> 1)) ^ (lane & 15);
        *(uint2*)(PbB + (wq0 + (lane & 15)) * 256 + (blk << 4) + ((g & 1) << 3)) = wrd;
    }
    ssum += __shfl_xor(ssum, 16);
    ssum += __shfl_xor(ssum, 32);
    if (lane < 16)
        lg[((size_t)bh * T_ + tq) * 4 + rnd] = m + __logf(ssum);

    f32x4 pacc[4];
#pragma unroll
    for (int dt = 0; dt < 4; ++dt) pacc[dt] = (f32x4){0.f, 0.f, 0.f, 0.f};
#pragma unroll
    for (int s = 0; s < 4; ++s) {
        int xr = ((s * 4 + g) ^ (lane & 15)) << 4;
        short8 pf = *(const short8*)(PbB + (wq0 + (lane & 15)) * 256 + xr);
#pragma unroll
        for (int dt = 0; dt < 4; ++dt) {
            short8 vf = *(const short8*)(VtB + (dt * 16 + (lane & 15)) * 256 + xr);
            pacc[dt] = __builtin_amdgcn_mfma_f32_16x16x32_bf16(pf, vf, pacc[dt], 0, 0, 0);
        }
    }
    __syncthreads();

#pragma unroll
    for (int r = 0; r < 4; ++r) {
        float sr = __shfl(ssum, g * 4 + r);
        float inv = 1.0f / sr;
        int rowl = wq0 + g * 4 + r;
#pragma unroll
        for (int dt = 0; dt < 4; ++dt) {
            __hip_bfloat16 hv = __float2bfloat16(pacc[dt][r] * inv);
            ObU[rowl * 72 + dt * 16 + (lane & 15)] = *(unsigned short*)&hv;
        }
    }
    __syncthreads();

    {
        int rr = tid >> 2, seg = tid & 3;
        uint4 a = *(const uint4*)(ObU + rr * 72 + seg * 16);
        uint4 b = *(const uint4*)(ObU + rr * 72 + seg * 16 + 8);
        size_t jor = (size_t)bh * T_ + kvt[rr];
        uint4* dst = (uint4*)(o + jor * 256 + rnd * 64 + seg * 16);
        dst[0] = a; dst[1] = b;
    }
}

// ---------------- combine hash rounds via softmax(logits) -> bf16 ----------------
// o layout: [bh][t][rnd][64] bf16 ; lg layout: [bh][t][rnd] f32
__global__ __launch_bounds__(256) void k_combine(const __hip_bfloat16* __restrict__ o,
                                                 const float* __restrict__ lg,
                                                 __hip_bfloat16* __restrict__ att)
{
    __shared__ float ws[H_][8];
    int bt = blockIdx.x;
    int bI = bt >> 12;
    int t  = bt & (T_ - 1);
    int tid = threadIdx.x;
    if (tid < H_) {
        size_t base = ((size_t)(bI * H_ + tid) * T_ + t);
        float4 L = *(const float4*)(lg + base * 4);
        float M = fmaxf(fmaxf(L.x, L.y), fmaxf(L.z, L.w));
        float w0 = __expf(L.x - M), w1 = __expf(L.y - M), w2 = __expf(L.z - M), w3 = __expf(L.w - M);
        float inv = 1.0f / (w0 + w1 + w2 + w3);
        ws[tid][0] = w0 * inv; ws[tid][1] = w1 * inv; ws[tid][2] = w2 * inv; ws[tid][3] = w3 * inv;
    }
    __syncthreads();
#pragma unroll
    for (int it = 0; it < 2; ++it) {
        int e = it * 256 + tid;
        int h = e >> 6, f = e & 63;
        const __hip_bfloat16* op = o + ((size_t)(bI * H_ + h) * T_ + t) * 256;
        float val = __bfloat162float(op[f])       * ws[h][0]
                  + __bfloat162float(op[64 + f])  * ws[h][1]
                  + __bfloat162float(op[128 + f]) * ws[h][2]
                  + __bfloat162float(op[192 + f]) * ws[h][3];
        att[(size_t)bt * E_ + e] = __float2bfloat16(val);
    }
}

// ---------------- pooling + final linear ----------------
__global__ __launch_bounds__(256) void k_pool1(const float* __restrict__ x1, const float* __restrict__ x2,
                                               float* __restrict__ part)
{
    int blk = blockIdx.x;
    int bI = blk >> 5, tc = blk & 31;
    int t0 = tc * 128;
    for (int e = threadIdx.x; e < E_; e += 256) {
        float s = 0.f;
        for (int t = t0; t < t0 + 128; ++t) {
            size_t idx = ((size_t)bI * T_ + t) * E_ + e;
            s += x1[idx] + x2[idx];
        }
        part[((size_t)bI * 32 + tc) * E_ + e] = s;
    }
}

__global__ __launch_bounds__(256) void k_final(const float* __restrict__ part, const float* __restrict__ wf,
                                               const float* __restrict__ bf, float* __restrict__ out)
{
    __shared__ float pooled[B_ * E_];
    int tid = threadIdx.x;
    for (int i = tid; i < B_ * E_; i += 256) {
        int bI = i >> 9, e = i & 511;
        float s = 0.f;
        for (int c2 = 0; c2 < 32; ++c2) s += part[((size_t)bI * 32 + c2) * E_ + e];
        pooled[i] = s * (0.5f / T_);
    }
    __syncthreads();
    if (tid < B_ * NCLASS_) {
        int bI = tid / NCLASS_, cl = tid % NCLASS_;
        float s = bf[cl];
        for (int e = 0; e < E_; ++e) s += pooled[bI * E_ + e] * wf[(size_t)e * NCLASS_ + cl];
        out[tid] = s;
    }
}

// ---------------- orchestration ----------------
extern "C" void kernel_launch(void* const* d_in, const int* in_sizes, int n_in,
                              void* d_out, int out_size, void* d_ws, size_t ws_size,
                              hipStream_t stream)
{
    const int*   X    = (const int*)d_in[0];
    const float* TOK  = (const float*)d_in[1];
    const float* POS  = (const float*)d_in[2];
    const float* ROT  = (const float*)d_in[3];
    const float* LN1G = (const float*)d_in[4];
    const float* LN1B = (const float*)d_in[5];
    const float* WQK  = (const float*)d_in[6];
    const float* WV   = (const float*)d_in[7];
    const float* WO   = (const float*)d_in[8];
    const float* BO   = (const float*)d_in[9];
    const float* LN2G = (const float*)d_in[10];
    const float* LN2B = (const float*)d_in[11];
    const float* WF1  = (const float*)d_in[12];
    const float* BF1  = (const float*)d_in[13];
    const float* WF2  = (const float*)d_in[14];
    const float* BF2  = (const float*)d_in[15];
    const float* WFIN = (const float*)d_in[16];
    const float* BFIN = (const float*)d_in[17];

    float* ws = (float*)d_ws;
    const size_t S = (size_t)B_ * T_ * E_;
    float* x1   = ws;
    float* x2   = x1 + S;
    float* qkb  = x2 + S;
    float* vb   = qkb + S;                 // unused (kept for layout stability)
    float* bigf = vb + S;
    float* lgb  = bigf + 2 * S;
    float* part = lgb + (size_t)BH_ * NT_;
    __hip_bfloat16* lnbh  = (__hip_bfloat16*)(part + (size_t)B_ * 32 * E_);
    __hip_bfloat16* lnbl  = lnbh + S;
    __hip_bfloat16* attnb = lnbl + S;
    int*   stb  = (int*)(attnb + S);
    __hip_bfloat16* WTbase = (__hip_bfloat16*)(stb + (size_t)BH_ * NT_);
    __hip_bfloat16* big    = (__hip_bfloat16*)bigf;

    const size_t W55 = (size_t)512 * 512;
    const size_t WFF = (size_t)2048 * 512;
    __hip_bfloat16* WTqk_hi = WTbase;
    __hip_bfloat16* WTqk_lo = WTqk_hi + 4 * W55;
    __hip_bfloat16* WTv     = WTqk_lo + 4 * W55;
    __hip_bfloat16* WTo     = WTv     + 4 * W55;
    __hip_bfloat16* WTf1    = WTo     + 4 * W55;
    __hip_bfloat16* WTf2    = WTf1    + 4 * WFF;
    unsigned char*  bktb    = (unsigned char*)(WTf2 + 4 * WFF);
    __hip_bfloat16* qh      = (__hip_bfloat16*)(bktb + (size_t)BH_ * NHASH_ * T_);
    __hip_bfloat16* khb     = qh  + (size_t)BH_ * T_ * 64;
    __hip_bfloat16* vhb     = khb + (size_t)BH_ * T_ * 64;
    __hip_bfloat16* rswzh   = vhb + (size_t)BH_ * T_ * 64;   // 4 layers x 8192 bf16
    __hip_bfloat16* rswzl   = rswzh + 4 * 8192;

    // batched weight prep: layer dim in blockIdx.z / blockIdx.x (24 launches -> 6)
    k_wprep<true ><<<dim3(16, 16, 4), 256, 0, stream>>>(WQK, WTqk_hi, WTqk_lo, 512, 512);
    k_wprep<false><<<dim3(16, 16, 4), 256, 0, stream>>>(WV, WTv, nullptr, 512, 512);
    k_wprep<false><<<dim3(16, 16, 4), 256, 0, stream>>>(WO, WTo, nullptr, 512, 512);
    k_wprep<false><<<dim3(64, 16, 4), 256, 0, stream>>>(WF1, WTf1, nullptr, 512, 2048);
    k_wprep<false><<<dim3(16, 64, 4), 256, 0, stream>>>(WF2, WTf2, nullptr, 2048, 512);
    k_rotprep<<<4, 256, 0, stream>>>(ROT, rswzh, rswzl);

    const int g512_64 = (512 / 128) * ((B_ * T_) / 64);   // 512 blocks (TM=64)
    const int gqk     = ((B_ * T_) / 64) * (512 / 64);    // 1024 blocks (64x64 QK)
    const int gff1    = ((B_ * T_) / 128) * (FF_ / 128);  // 1024 blocks (TM=128 FF1)

    k_embed<<<B_ * T_, 128, 0, stream>>>(X, TOK, POS, x1, x2);
    for (int d = 0; d < DEPTH_; ++d) {
        // --- attention half: x1 += attn(ln1(x2)) ---
        k_ln<true><<<B_ * T_, 128, 0, stream>>>(x2, LN1G + (size_t)d * E_, LN1B + (size_t)d * E_, lnbh, lnbl);
        k_qk64<<<gqk, 256, 0, stream>>>(lnbh, lnbl, WTqk_hi + d * W55, WTqk_lo + d * W55, qkb);
        k_mgemm<3, 0, 64><<<g512_64, 256, 0, stream>>>(lnbh, WTv + d * W55, nullptr, vhb, 512, 512, 2);
        k_hash<<<dim3(BH_, T_ / 128), 256, 0, stream>>>(qkb, rswzh + d * 8192, rswzl + d * 8192,
                                                        bktb, qh, khb);
        k_sort<<<BH_ * NHASH_, 256, 0, stream>>>(bktb, stb);
        k_attn<<<BH_ * C_, 256, 0, stream>>>(qh, khb, vhb, stb, big, lgb);
        k_combine<<<B_ * T_, 256, 0, stream>>>(big, lgb, attnb);
        k_mgemm<1, 1, 64><<<g512_64, 256, 0, stream>>>(attnb, WTo + d * W55, BO + (size_t)d * E_, x1,
                                                       512, 512, 2);
        // --- ff half: x2 += ff(ln2(x1)) ---
        k_ln<false><<<B_ * T_, 128, 0, stream>>>(x1, LN2G + (size_t)d * E_, LN2B + (size_t)d * E_, lnbh, nullptr);
        k_mgemm<2, 1, 128><<<gff1, 256, 0, stream>>>(lnbh, WTf1 + d * WFF, BF1 + (size_t)d * FF_, big,
                                                     2048, 512, 4);
        k_mgemm<1, 1, 64><<<g512_64, 256, 0, stream>>>(big, WTf2 + d * WFF, BF2 + (size_t)d * E_, x2,
                                                       512, 2048, 2);
    }
    k_pool1<<<B_ * 32, 256, 0, stream>>>(x1, x2, part);
    k_final<<<1, 256, 0, stream>>>(part, WFIN, BFIN, (float*)d_out);
}

// Round 8
// 755.788 us; speedup vs baseline: 1.0181x; 1.0181x over previous
//
#include <hip/hip_runtime.h>
#include <hip/hip_bf16.h>
#include <math.h>

// ---- problem dims ----
#define B_      2
#define T_      4096
#define E_      512
#define H_      8
#define DH_     64
#define DEPTH_  4
#define NHASH_  4
#define BUCKET_ 64
#define NB_     64
#define NB2_    32
#define C_      (NHASH_*NB_)      // 256 chunks per bh
#define BH_     (B_*H_)           // 16
#define NT_     (NHASH_*T_)       // 16384
#define FF_     2048
#define NCLASS_ 10
#define MASKV   (-1e9f)
#define SELFV   (-5e4f)

typedef __attribute__((ext_vector_type(8))) short short8;   // 8 bf16 = 4 VGPR
typedef __attribute__((ext_vector_type(4))) float f32x4;

__device__ __forceinline__ void gload_lds16(const void* g, void* l) {
    __builtin_amdgcn_global_load_lds(
        (const __attribute__((address_space(1))) void*)g,
        (__attribute__((address_space(3))) void*)l,
        16, 0, 0);
}

__device__ __forceinline__ unsigned pk2(float a, float b) {
    __hip_bfloat16 ha = __float2bfloat16(a), hb = __float2bfloat16(b);
    unsigned short ua = *(unsigned short*)&ha, ub = *(unsigned short*)&hb;
    return (unsigned)ua | ((unsigned)ub << 16);
}

// ---------------- embed: h = tok_emb[x] + pos_emb ----------------
__global__ __launch_bounds__(128) void k_embed(const int* __restrict__ x, const float* __restrict__ tok,
                                               const float* __restrict__ pos, float* __restrict__ x1,
                                               float* __restrict__ x2)
{
    int bt = blockIdx.x;
    int t  = bt & (T_ - 1);
    int id = x[bt];
    float4 tv = ((const float4*)(tok + (size_t)id * E_))[threadIdx.x];
    float4 pv = ((const float4*)(pos + (size_t)t * E_))[threadIdx.x];
    float4 hv = make_float4(tv.x + pv.x, tv.y + pv.y, tv.z + pv.z, tv.w + pv.w);
    ((float4*)(x1 + (size_t)bt * E_))[threadIdx.x] = hv;
    ((float4*)(x2 + (size_t)bt * E_))[threadIdx.x] = hv;
}

// ---------------- layernorm over E=512 -> bf16 (hi) [+ bf16 residual (lo)] ----------------
template<bool LO>
__global__ __launch_bounds__(128) void k_ln(const float* __restrict__ in, const float* __restrict__ g,
                                            const float* __restrict__ b, __hip_bfloat16* __restrict__ out,
                                            __hip_bfloat16* __restrict__ outlo)
{
    int row = blockIdx.x, tid = threadIdx.x;
    float4 v = ((const float4*)(in + (size_t)row * E_))[tid];
    float s = v.x + v.y + v.z + v.w;
    float q = v.x * v.x + v.y * v.y + v.z * v.z + v.w * v.w;
#pragma unroll
    for (int d = 1; d < 64; d <<= 1) { s += __shfl_xor(s, d); q += __shfl_xor(q, d); }
    __shared__ float red[4];
    int w = tid >> 6;
    if ((tid & 63) == 0) { red[w * 2] = s; red[w * 2 + 1] = q; }
    __syncthreads();
    s = red[0] + red[2]; q = red[1] + red[3];
    float mean = s * (1.0f / E_);
    float var  = q * (1.0f / E_) - mean * mean;
    float rstd = rsqrtf(var + 1e-5f);
    float4 gv = ((const float4*)g)[tid];
    float4 bv = ((const float4*)b)[tid];
    float o0 = (v.x - mean) * rstd * gv.x + bv.x;
    float o1 = (v.y - mean) * rstd * gv.y + bv.y;
    float o2 = (v.z - mean) * rstd * gv.z + bv.z;
    float o3 = (v.w - mean) * rstd * gv.w + bv.w;
    __hip_bfloat16* op = out + (size_t)row * E_ + tid * 4;
    __hip_bfloat16 h0 = __float2bfloat16(o0), h1 = __float2bfloat16(o1);
    __hip_bfloat16 h2 = __float2bfloat16(o2), h3 = __float2bfloat16(o3);
    op[0] = h0; op[1] = h1; op[2] = h2; op[3] = h3;
    if (LO) {
        __hip_bfloat16* lp = outlo + (size_t)row * E_ + tid * 4;
        lp[0] = __float2bfloat16(o0 - __bfloat162float(h0));
        lp[1] = __float2bfloat16(o1 - __bfloat162float(h1));
        lp[2] = __float2bfloat16(o2 - __bfloat162float(h2));
        lp[3] = __float2bfloat16(o3 - __bfloat162float(h3));
    }
}

// ------- weight transpose + bf16 cast (all 4 layers batched via blockIdx.z) -------
template<bool SPLIT>
__global__ __launch_bounds__(256) void k_wprep(const float* __restrict__ W, __hip_bfloat16* __restrict__ WT,
                                               __hip_bfloat16* __restrict__ WTlo, int K, int N)
{
    __shared__ float tile[32][33];
    size_t lofs = (size_t)blockIdx.z * K * N;
    W  += lofs;
    WT += lofs;
    if (SPLIT) WTlo += lofs;
    int n0 = blockIdx.x * 32, k0 = blockIdx.y * 32;
    int tx = threadIdx.x & 31, ty = threadIdx.x >> 5;
#pragma unroll
    for (int i = 0; i < 4; ++i) {
        int k = ty + i * 8;
        tile[k][tx] = W[(size_t)(k0 + k) * N + n0 + tx];
    }
    __syncthreads();
#pragma unroll
    for (int i = 0; i < 4; ++i) {
        int n = ty + i * 8;
        float v = tile[tx][n];
        __hip_bfloat16 hv = __float2bfloat16(v);
        WT[(size_t)(n0 + n) * K + k0 + tx] = hv;
        if (SPLIT)
            WTlo[(size_t)(n0 + n) * K + k0 + tx] = __float2bfloat16(v - __bfloat162float(hv));
    }
}

// ---- rot prep (4 layers batched: blockIdx.x = layer) ----
__global__ __launch_bounds__(256) void k_rotprep(const float* __restrict__ rot,
                                                 __hip_bfloat16* __restrict__ rhs,
                                                 __hip_bfloat16* __restrict__ rls)
{
    int d = blockIdx.x;
    rot += (size_t)d * 64 * 128;
    rhs += (size_t)d * 8192;
    rls += (size_t)d * 8192;
    int tid = threadIdx.x;
    for (int idx = tid; idx < 128 * 64; idx += 256) {
        int row = idx >> 6, f = idx & 63;
        float v = rot[(size_t)f * 128 + row];
        __hip_bfloat16 hv = __float2bfloat16(v);
        __hip_bfloat16 lv = __float2bfloat16(v - __bfloat162float(hv));
        int b = f >> 3;
        int off = row * 64 + (((b ^ (row & 7)) << 3) | (f & 7));
        rhs[off] = hv;
        rls[off] = lv;
    }
}

// fast exact-GELU: erf via Abramowitz-Stegun 7.1.26 (|eps| <= 1.5e-7), one v_exp + v_rcp
__device__ __forceinline__ float geluf(float x) {
    float ax = fabsf(x) * 0.70710678118654752f;
    float t  = __builtin_amdgcn_rcpf(1.0f + 0.3275911f * ax);
    float poly = t * (0.254829592f + t * (-0.284496736f + t * (1.421413741f +
                 t * (-1.453152027f + t * 1.061405429f))));
    float e = __expf(-ax * ax);
    float erfax = 1.0f - poly * e;
    float erfx = copysignf(erfax, x);
    return 0.5f * x * (1.0f + erfx);
}

// ---------------- bf16 MFMA GEMM: 2-phase dbuf, BK=64, XCD swizzle ----
// OUTK: 1 = f32 ACC store, 2 = bf16 GELU store, 3 = bf16 store to head-gathered vh layout.
template<int OUTK, int BIAS, int TM>
__global__ __launch_bounds__(256) void k_mgemm(const __hip_bfloat16* __restrict__ A,
                                               const __hip_bfloat16* __restrict__ WT,
                                               const float* __restrict__ bias, void* __restrict__ Cout,
                                               int N, int K, int nbnShift)
{
    constexpr int MF = TM / 32;               // A fragments / wave (and A gloads / thread)
    constexpr int ABYTES = TM * 128;          // per-buffer A bytes (TM rows x 64 k x 2B)
    __shared__ __align__(16) char smem[2 * ABYTES + 32768];
    char* BbBase = smem + 2 * ABYTES;

    int tid = threadIdx.x;
    int lane = tid & 63, wv = tid >> 6, w = wv;
    int nwg = gridDim.x;
    int bid = blockIdx.x;
    int swz = (bid & 7) * (nwg >> 3) + (bid >> 3);
    int nmask = (1 << nbnShift) - 1;
    int m0 = (swz >> nbnShift) * TM, n0 = (swz & nmask) * 128;
    int wm = (w >> 1) * (TM / 2), wn = (w & 1) * 64;

    // staging sources: dest slot d = (wv + g*4)*64 + lane (wave-contiguous); row = d>>3, slot = d&7
    const __hip_bfloat16* aSg[MF];
    int aDd[MF];
#pragma unroll
    for (int g = 0; g < MF; ++g) {
        int d = (wv + g * 4) * 64 + lane;
        int row = d >> 3, slot = d & 7;
        int c = (slot - ((row >> 1) & 7)) & 7;
        aSg[g] = A + (size_t)(m0 + row) * K + c * 8;
        aDd[g] = d * 16;
    }
    const __hip_bfloat16* bSg[4];
    int bDd[4];
#pragma unroll
    for (int g = 0; g < 4; ++g) {
        int d = (wv + g * 4) * 64 + lane;
        int row = d >> 3, slot = d & 7;
        int c = (slot - ((row >> 1) & 7)) & 7;
        bSg[g] = WT + (size_t)(n0 + row) * K + c * 8;
        bDd[g] = d * 16;
    }

    int cch = lane >> 4;
    int aoff[MF][2], boff[4][2];
#pragma unroll
    for (int f = 0; f < MF; ++f) {
        int ar = wm + f * 16 + (lane & 15);
        int rot = (ar >> 1) & 7;
#pragma unroll
        for (int h = 0; h < 2; ++h)
            aoff[f][h] = ar * 128 + (((h * 4 + cch) + rot) & 7) * 16;
    }
#pragma unroll
    for (int f = 0; f < 4; ++f) {
        int br = wn + f * 16 + (lane & 15);
        int rot = (br >> 1) & 7;
#pragma unroll
        for (int h = 0; h < 2; ++h)
            boff[f][h] = br * 128 + (((h * 4 + cch) + rot) & 7) * 16;
    }

    f32x4 acc[MF][4];
#pragma unroll
    for (int i = 0; i < MF; ++i)
#pragma unroll
        for (int j = 0; j < 4; ++j) acc[i][j] = (f32x4){0.f, 0.f, 0.f, 0.f};

    const int NS = K >> 6;
    {
#pragma unroll
        for (int g = 0; g < MF; ++g) gload_lds16(aSg[g], smem + aDd[g]);
#pragma unroll
        for (int g = 0; g < 4; ++g)  gload_lds16(bSg[g], BbBase + bDd[g]);
    }
    __syncthreads();
    for (int s = 0; s < NS; ++s) {
        int cur = s & 1;
        if (s + 1 < NS) {
            int nb = cur ^ 1;
            int kk = (s + 1) * 64;
            char* Abn = smem + nb * ABYTES;
            char* Bbn = BbBase + nb * 16384;
#pragma unroll
            for (int g = 0; g < MF; ++g) gload_lds16(aSg[g] + kk, Abn + aDd[g]);
#pragma unroll
            for (int g = 0; g < 4; ++g)  gload_lds16(bSg[g] + kk, Bbn + bDd[g]);
        }
        const char* Ab = smem + cur * ABYTES;
        const char* Bb = BbBase + cur * 16384;
#pragma unroll
        for (int h = 0; h < 2; ++h) {
            short8 af[MF], bfr[4];
#pragma unroll
            for (int f = 0; f < MF; ++f) af[f] = *(const short8*)(Ab + aoff[f][h]);
#pragma unroll
            for (int f = 0; f < 4; ++f)  bfr[f] = *(const short8*)(Bb + boff[f][h]);
#pragma unroll
            for (int i = 0; i < MF; ++i)
#pragma unroll
                for (int j = 0; j < 4; ++j)
                    acc[i][j] = __builtin_amdgcn_mfma_f32_16x16x32_bf16(af[i], bfr[j], acc[i][j], 0, 0, 0);
        }
        __syncthreads();
    }

    int g = lane >> 4;
    if (OUTK == 2 || OUTK == 3) {
        unsigned short* Ot = (unsigned short*)smem;
#pragma unroll
        for (int i = 0; i < MF; ++i) {
#pragma unroll
            for (int j = 0; j < 4; ++j) {
                int col = wn + j * 16 + (lane & 15);
                float bv = BIAS ? bias[n0 + col] : 0.f;
#pragma unroll
                for (int q = 0; q < 4; ++q) {
                    int row = wm + i * 16 + g * 4 + q;
                    float vv = acc[i][j][q] + bv;
                    if (OUTK == 2) vv = geluf(vv);
                    __hip_bfloat16 hv = __float2bfloat16(vv);
                    Ot[row * 128 + (((col >> 3) ^ (row & 7)) << 3) + (col & 7)] = *(unsigned short*)&hv;
                }
            }
        }
        __syncthreads();
#pragma unroll
        for (int u = 0; u < TM / 16; ++u) {
            int f = u * 256 + tid;
            int row = f >> 4, cblk = f & 15;
            uint4 v = *(const uint4*)(Ot + row * 128 + ((cblk ^ (row & 7)) << 3));
            if (OUTK == 2) {
                *(uint4*)((__hip_bfloat16*)Cout + (size_t)(m0 + row) * N + n0 + cblk * 8) = v;
            } else {
                int mrow = m0 + row;
                int t = mrow & (T_ - 1), bI = mrow >> 12;
                int col = n0 + cblk * 8;
                int h = col >> 6, fin = col & 63;
                *(uint4*)((__hip_bfloat16*)Cout + ((size_t)(bI * H_ + h) * T_ + t) * 64 + fin) = v;
            }
        }
    } else {
        float* Ot = (float*)smem;
        float* Cb = (float*)Cout;
#pragma unroll
        for (int i = 0; i < MF; ++i) {
#pragma unroll
            for (int j = 0; j < 4; ++j) {
                int col = wn + j * 16 + (lane & 15);
#pragma unroll
                for (int q = 0; q < 4; ++q) {
                    int row = wm + i * 16 + g * 4 + q;
                    Ot[row * 128 + (((col >> 2) ^ (row & 7)) << 2) + (col & 3)] = acc[i][j][q];
                }
            }
        }
        __syncthreads();
#pragma unroll
        for (int u = 0; u < 8; ++u) {
            int f = u * 256 + tid;
            int row = f >> 5, c4 = f & 31;
            float4 v = *(const float4*)(Ot + row * 128 + ((c4 ^ (row & 7)) << 2));
            if (BIAS) {
                float4 bv = *(const float4*)(bias + n0 + c4 * 4);
                v.x += bv.x; v.y += bv.y; v.z += bv.z; v.w += bv.w;
            }
            float* cp = Cb + (size_t)(m0 + row) * N + n0 + c4 * 4;
            float4 old = *(const float4*)cp;
            v.x += old.x; v.y += old.y; v.z += old.z; v.w += old.w;
            *(float4*)cp = v;
        }
    }
}

// ---------------- 256x256 8-phase bf16 GEMM (T2+T3+T4+T5) with GELU bf16 epilogue -------------
#define STG_A(buf, kt, h) \
    gload_lds16(aSrc + (size_t)((h) * 128) * K + (kt) * 64,      smem + (buf) * 32768 + (h) * 16384 + tid * 16); \
    gload_lds16(aSrc + (size_t)((h) * 128 + 64) * K + (kt) * 64, smem + (buf) * 32768 + (h) * 16384 + 8192 + tid * 16);
#define STG_B(buf, kt, h) \
    gload_lds16(bSrc + (size_t)((h) * 128) * K + (kt) * 64,      smem + 65536 + (buf) * 32768 + (h) * 16384 + tid * 16); \
    gload_lds16(bSrc + (size_t)((h) * 128 + 64) * K + (kt) * 64, smem + 65536 + (buf) * 32768 + (h) * 16384 + 8192 + tid * 16);

#define PHASE8(buf, MH, NH, RA, RB, STAGE, GATE) do {                                             \
    const char* Ab_ = smem + (buf) * 32768;                                                       \
    const char* Bb_ = smem + 65536 + (buf) * 32768;                                               \
    STAGE                                                                                         \
    if (RA) {                                                                                     \
        _Pragma("unroll")                                                                         \
        for (int mf = 0; mf < 4; ++mf) {                                                          \
            int row = arow + (MH) * 128 + mf * 16;                                                \
            aF[mf][0] = *(const short8*)(Ab_ + row * 128 + sw0);                                  \
            aF[mf][1] = *(const short8*)(Ab_ + row * 128 + sw1);                                  \
        }                                                                                         \
    }                                                                                             \
    if (RB) {                                                                                     \
        _Pragma("unroll")                                                                         \
        for (int nf = 0; nf < 2; ++nf) {                                                          \
            int row = brow + (NH) * 128 + nf * 16;                                                \
            bF[nf][0] = *(const short8*)(Bb_ + row * 128 + sw0);                                  \
            bF[nf][1] = *(const short8*)(Bb_ + row * 128 + sw1);                                  \
        }                                                                                         \
    }                                                                                             \
    GATE                                                                                          \
    __builtin_amdgcn_s_barrier();                                                                 \
    asm volatile("s_waitcnt lgkmcnt(0)" ::: "memory");                                            \
    __builtin_amdgcn_sched_barrier(0);                                                            \
    __builtin_amdgcn_s_setprio(1);                                                                \
    _Pragma("unroll")                                                                             \
    for (int mf = 0; mf < 4; ++mf)                                                                \
        _Pragma("unroll")                                                                         \
        for (int nf = 0; nf < 2; ++nf) {                                                          \
            acc[MH][NH][mf][nf] = __builtin_amdgcn_mfma_f32_16x16x32_bf16(aF[mf][0], bF[nf][0], acc[MH][NH][mf][nf], 0, 0, 0); \
            acc[MH][NH][mf][nf] = __builtin_amdgcn_mfma_f32_16x16x32_bf16(aF[mf][1], bF[nf][1], acc[MH][NH][mf][nf], 0, 0, 0); \
        }                                                                                         \
    __builtin_amdgcn_s_setprio(0);                                                                \
    __builtin_amdgcn_s_barrier();                                                                 \
} while (0)

__global__ __launch_bounds__(512, 2) void k_gemm256_gelu(const __hip_bfloat16* __restrict__ A,
                                                         const __hip_bfloat16* __restrict__ WT,
                                                         const float* __restrict__ bias,
                                                         __hip_bfloat16* __restrict__ Cout,
                                                         int N, int K, int nShift)
{
    __shared__ __align__(16) char smem[131072];
    const int NT = K >> 6;
    int tid = threadIdx.x;
    int lane = tid & 63, w = tid >> 6;
    int lane7 = lane & 7, cch = lane >> 4;
    int nwg = gridDim.x;
    int bid = blockIdx.x;
    int swz = (bid & 7) * (nwg >> 3) + (bid >> 3);
    int m0 = (swz >> nShift) * 256;
    int n0 = (swz & ((1 << nShift) - 1)) * 256;

    int rstg = tid >> 3;
    int kcstg = (tid & 7) ^ (rstg & 7);
    const __hip_bfloat16* aSrc = A  + (size_t)(m0 + rstg) * K + kcstg * 8;
    const __hip_bfloat16* bSrc = WT + (size_t)(n0 + rstg) * K + kcstg * 8;

    int arow = (w >> 2) * 64 + (lane & 15);
    int brow = (w & 3) * 32 + (lane & 15);
    int sw0 = (cch ^ lane7) << 4;
    int sw1 = ((4 + cch) ^ lane7) << 4;

    f32x4 acc[2][2][4][2];
#pragma unroll
    for (int a2 = 0; a2 < 2; ++a2)
#pragma unroll
        for (int b2 = 0; b2 < 2; ++b2)
#pragma unroll
            for (int c2 = 0; c2 < 4; ++c2)
#pragma unroll
                for (int d2 = 0; d2 < 2; ++d2) acc[a2][b2][c2][d2] = (f32x4){0.f, 0.f, 0.f, 0.f};

    short8 aF[4][2], bF[2][2];   // register-cached fragments, persist across phases

    STG_A(0, 0, 0) STG_A(0, 0, 1) STG_B(0, 0, 0) STG_B(0, 0, 1)
    if (NT > 1) { STG_A(1, 1, 0) STG_B(1, 1, 1) }
    if (NT > 1) asm volatile("s_waitcnt vmcnt(4)" ::: "memory");
    else        asm volatile("s_waitcnt vmcnt(0)" ::: "memory");
    __builtin_amdgcn_s_barrier();

    for (int t = 0; t < NT; ++t) {
        int buf = t & 1;
        PHASE8(buf, 0, 0, 1, 1, { if (t + 1 < NT) { STG_A(buf ^ 1, t + 1, 1) } }, {});
        PHASE8(buf, 0, 1, 0, 1, { if (t + 1 < NT) { STG_B(buf ^ 1, t + 1, 0) } }, {});
        PHASE8(buf, 1, 1, 1, 0, { if (t + 2 < NT) { STG_A(buf, t + 2, 0) } }, {});
        PHASE8(buf, 1, 0, 0, 1, { if (t + 2 < NT) { STG_B(buf, t + 2, 1) } },
               { if (t + 2 < NT)      asm volatile("s_waitcnt vmcnt(4)" ::: "memory");
                 else if (t + 1 < NT) asm volatile("s_waitcnt vmcnt(0)" ::: "memory"); });
    }

    unsigned short* Ot = (unsigned short*)smem;
    int g = lane >> 4;
#pragma unroll
    for (int mh = 0; mh < 2; ++mh)
#pragma unroll
        for (int nh = 0; nh < 2; ++nh)
#pragma unroll
            for (int nf = 0; nf < 2; ++nf) {
                int coll = nh * 128 + (w & 3) * 32 + nf * 16 + (lane & 15);
                float bv = bias[n0 + coll];
#pragma unroll
                for (int mf = 0; mf < 4; ++mf)
#pragma unroll
                    for (int q = 0; q < 4; ++q) {
                        int rowl = mh * 128 + (w >> 2) * 64 + mf * 16 + g * 4 + q;
                        float vv = geluf(acc[mh][nh][mf][nf][q] + bv);
                        __hip_bfloat16 hv = __float2bfloat16(vv);
                        Ot[rowl * 256 + ((((coll >> 4) ^ (rowl & 7)) << 4) | (coll & 15))] = *(unsigned short*)&hv;
                    }
            }
    __syncthreads();
#pragma unroll
    for (int u = 0; u < 16; ++u) {
        int f = u * 512 + tid;
        int rowl = f >> 5, c16 = f & 31;
        uint4 v = *(const uint4*)(Ot + rowl * 256 + ((((c16 >> 1) ^ (rowl & 7)) << 4) | ((c16 & 1) << 3)));
        *(uint4*)(Cout + (size_t)(m0 + rowl) * N + n0 + c16 * 8) = v;
    }
}
#undef PHASE8
#undef STG_A
#undef STG_B

// ---------------- fused split-bf16 QK GEMM: BK=64, 64x64 tiles, rotation-swizzled LDS ---------
// qk = Ah*Bh + Ah*Bl + Al*Bh ; accumulation order per 32-k chunk identical to prior kernel.
__global__ __launch_bounds__(256) void k_qk64(const __hip_bfloat16* __restrict__ Ah,
                                              const __hip_bfloat16* __restrict__ Al,
                                              const __hip_bfloat16* __restrict__ Bh,
                                              const __hip_bfloat16* __restrict__ Bl,
                                              float* __restrict__ Cout)
{
    const int N = 512, K = 512;
    __shared__ __align__(16) char smem[65536];   // 2 bufs x 32KB (Ah|Al|Bh|Bl 8KB each)
    int tid = threadIdx.x;
    int lane = tid & 63, wv = tid >> 6;
    int nwg = gridDim.x;                          // 1024
    int bid = blockIdx.x;
    int swz = (bid & 7) * (nwg >> 3) + (bid >> 3);
    int m0 = (swz >> 3) * 64, n0 = (swz & 7) * 64;
    int wm = (wv >> 1) * 32, wn = (wv & 1) * 32;

    // staging: per array 512 slots of 16B; dest d = (wv + g*4)*64 + lane; row=d>>3, slot=d&7
    const __hip_bfloat16* sAh[2]; const __hip_bfloat16* sAl[2];
    const __hip_bfloat16* sBh[2]; const __hip_bfloat16* sBl[2];
    int dOf[2];
#pragma unroll
    for (int g = 0; g < 2; ++g) {
        int d = (wv + g * 4) * 64 + lane;
        int row = d >> 3, slot = d & 7;
        int c = (slot - ((row >> 1) & 7)) & 7;
        dOf[g] = d * 16;
        sAh[g] = Ah + (size_t)(m0 + row) * K + c * 8;
        sAl[g] = Al + (size_t)(m0 + row) * K + c * 8;
        sBh[g] = Bh + (size_t)(n0 + row) * K + c * 8;
        sBl[g] = Bl + (size_t)(n0 + row) * K + c * 8;
    }

    int cch = lane >> 4;
    int aoff[2][2], boff[2][2];     // [frag][half]
#pragma unroll
    for (int f = 0; f < 2; ++f) {
        int ar = wm + f * 16 + (lane & 15);
        int rta = (ar >> 1) & 7;
        int br = wn + f * 16 + (lane & 15);
        int rtb = (br >> 1) & 7;
#pragma unroll
        for (int h = 0; h < 2; ++h) {
            aoff[f][h] = ar * 128 + (((h * 4 + cch) + rta) & 7) * 16;
            boff[f][h] = br * 128 + (((h * 4 + cch) + rtb) & 7) * 16;
        }
    }

    f32x4 acc[2][2];
#pragma unroll
    for (int i = 0; i < 2; ++i)
#pragma unroll
        for (int j = 0; j < 2; ++j) acc[i][j] = (f32x4){0.f, 0.f, 0.f, 0.f};

#define QK_STG(buf, kk)                                              \
    { char* bb = smem + (buf) * 32768;                               \
      _Pragma("unroll")                                              \
      for (int g = 0; g < 2; ++g) {                                  \
          gload_lds16(sAh[g] + (kk), bb + dOf[g]);                   \
          gload_lds16(sAl[g] + (kk), bb + 8192  + dOf[g]);           \
          gload_lds16(sBh[g] + (kk), bb + 16384 + dOf[g]);           \
          gload_lds16(sBl[g] + (kk), bb + 24576 + dOf[g]);           \
      } }

    QK_STG(0, 0)
    __syncthreads();
    const int NS = K >> 6;    // 8
    for (int s = 0; s < NS; ++s) {
        int cur = s & 1;
        if (s + 1 < NS) QK_STG(cur ^ 1, (s + 1) * 64)
        const char* bb = smem + cur * 32768;
#pragma unroll
        for (int h = 0; h < 2; ++h) {
            short8 afh[2], afl[2], bfh[2], bfl[2];
#pragma unroll
            for (int f = 0; f < 2; ++f) {
                afh[f] = *(const short8*)(bb + aoff[f][h]);
                afl[f] = *(const short8*)(bb + 8192  + aoff[f][h]);
                bfh[f] = *(const short8*)(bb + 16384 + boff[f][h]);
                bfl[f] = *(const short8*)(bb + 24576 + boff[f][h]);
            }
#pragma unroll
            for (int i = 0; i < 2; ++i)
#pragma unroll
                for (int j = 0; j < 2; ++j) {
                    acc[i][j] = __builtin_amdgcn_mfma_f32_16x16x32_bf16(afh[i], bfh[j], acc[i][j], 0, 0, 0);
                    acc[i][j] = __builtin_amdgcn_mfma_f32_16x16x32_bf16(afh[i], bfl[j], acc[i][j], 0, 0, 0);
                    acc[i][j] = __builtin_amdgcn_mfma_f32_16x16x32_bf16(afl[i], bfh[j], acc[i][j], 0, 0, 0);
                }
        }
        __syncthreads();
    }
#undef QK_STG

    int g = lane >> 4;
    float* Ot = (float*)smem;
#pragma unroll
    for (int i = 0; i < 2; ++i)
#pragma unroll
        for (int j = 0; j < 2; ++j) {
            int col = wn + j * 16 + (lane & 15);
#pragma unroll
            for (int q = 0; q < 4; ++q) {
                int row = wm + i * 16 + g * 4 + q;
                Ot[row * 64 + (((col >> 2) ^ (row & 7)) << 2) + (col & 3)] = acc[i][j][q];
            }
        }
    __syncthreads();
#pragma unroll
    for (int u = 0; u < 4; ++u) {
        int f = u * 256 + tid;
        int row = f >> 4, c4 = f & 15;
        float4 v = *(const float4*)(Ot + row * 64 + ((c4 ^ (row & 7)) << 2));
        *(float4*)(Cout + (size_t)(m0 + row) * N + n0 + c4 * 4) = v;
    }
}

// ---------------- MFMA LSH hashing: 128 tokens/block, rotated = mfma(rot, q), + q/k' emission --
__global__ __launch_bounds__(256) void k_hash(const float* __restrict__ qk,
                                              const __hip_bfloat16* __restrict__ rhs,
                                              const __hip_bfloat16* __restrict__ rls,
                                              unsigned char* __restrict__ bkt,
                                              __hip_bfloat16* __restrict__ qh,
                                              __hip_bfloat16* __restrict__ kh)
{
    __shared__ __align__(16) char smem[65536];
    char* RH = smem;            // [128][64] bf16 rot hi, XOR(row&7) swizzled (pre-swizzled image)
    char* RL = smem + 16384;    // rot lo
    char* QH = smem + 32768;    // [128][64] bf16 q hi, XOR(t&7)
    char* QL = smem + 49152;    // q lo
    int tid = threadIdx.x, lane = tid & 63, wv = tid >> 6;
    int bh = blockIdx.x, tc = blockIdx.y;       // grid (16, 32)
    int bI = bh >> 3, h = bh & 7;

#pragma unroll
    for (int it = 0; it < 4; ++it) {
        gload_lds16((const char*)rhs + it * 4096 + tid * 16, RH + it * 4096 + tid * 16);
        gload_lds16((const char*)rls + it * 4096 + tid * 16, RL + it * 4096 + tid * 16);
    }

    {
        int t = tid >> 1, half = tid & 1;
        int tg = tc * 128 + t;
        const float4* qsrc = (const float4*)(qk + ((size_t)(bI * T_ + tg)) * E_ + h * DH_ + half * 32);
        float4 q4[8];
        float n2 = 0.f;
#pragma unroll
        for (int j = 0; j < 8; ++j) {
            q4[j] = qsrc[j];
            n2 += q4[j].x * q4[j].x + q4[j].y * q4[j].y + q4[j].z * q4[j].z + q4[j].w * q4[j].w;
        }
        n2 += __shfl_xor(n2, 1);
        float sc = 0.125f / fmaxf(sqrtf(n2), 1e-12f);
        float qv[32];
#pragma unroll
        for (int j = 0; j < 8; ++j) {
            qv[4 * j] = q4[j].x; qv[4 * j + 1] = q4[j].y; qv[4 * j + 2] = q4[j].z; qv[4 * j + 3] = q4[j].w;
        }
        unsigned short hb[32], lb[32], kb[32];
#pragma unroll
        for (int j = 0; j < 32; ++j) {
            __hip_bfloat16 hv = __float2bfloat16(qv[j]);
            __hip_bfloat16 lv = __float2bfloat16(qv[j] - __bfloat162float(hv));
            __hip_bfloat16 kv = __float2bfloat16(qv[j] * sc);
            hb[j] = *(unsigned short*)&hv; lb[j] = *(unsigned short*)&lv; kb[j] = *(unsigned short*)&kv;
        }
        size_t ro = ((size_t)bh * T_ + tg) * 64 + half * 32;
        uint4* qdst = (uint4*)(qh + ro);
        uint4* kdst = (uint4*)(kh + ro);
#pragma unroll
        for (int j = 0; j < 4; ++j) {
            qdst[j] = *(uint4*)&hb[8 * j];
            kdst[j] = *(uint4*)&kb[8 * j];
        }
#pragma unroll
        for (int j = 0; j < 4; ++j) {
            int b = half * 4 + j;
            int xo = t * 128 + ((b ^ (t & 7)) << 4);
            *(uint4*)(QH + xo) = *(uint4*)&hb[8 * j];
            *(uint4*)(QL + xo) = *(uint4*)&lb[8 * j];
        }
    }
    __syncthreads();

#pragma unroll
    for (int sub = 0; sub < 2; ++sub) {
        int tl = wv * 32 + sub * 16 + (lane & 15);
        int g = lane >> 4;
        short8 qfh0 = *(const short8*)(QH + tl * 128 + ((g ^ (tl & 7)) << 4));
        short8 qfh1 = *(const short8*)(QH + tl * 128 + (((4 + g) ^ (tl & 7)) << 4));
        short8 qfl0 = *(const short8*)(QL + tl * 128 + ((g ^ (tl & 7)) << 4));
        short8 qfl1 = *(const short8*)(QL + tl * 128 + (((4 + g) ^ (tl & 7)) << 4));
        f32x4 sacc[8];
#pragma unroll
        for (int kt = 0; kt < 8; ++kt) sacc[kt] = (f32x4){0.f, 0.f, 0.f, 0.f};
#pragma unroll
        for (int kt = 0; kt < 8; ++kt) {
            int row = kt * 16 + (lane & 15);
            short8 rh0 = *(const short8*)(RH + row * 128 + ((g ^ (row & 7)) << 4));
            short8 rh1 = *(const short8*)(RH + row * 128 + (((4 + g) ^ (row & 7)) << 4));
            short8 rl0 = *(const short8*)(RL + row * 128 + ((g ^ (row & 7)) << 4));
            short8 rl1 = *(const short8*)(RL + row * 128 + (((4 + g) ^ (row & 7)) << 4));
            sacc[kt] = __builtin_amdgcn_mfma_f32_16x16x32_bf16(rh0, qfh0, sacc[kt], 0, 0, 0);
            sacc[kt] = __builtin_amdgcn_mfma_f32_16x16x32_bf16(rh1, qfh1, sacc[kt], 0, 0, 0);
            sacc[kt] = __builtin_amdgcn_mfma_f32_16x16x32_bf16(rl0, qfh0, sacc[kt], 0, 0, 0);
            sacc[kt] = __builtin_amdgcn_mfma_f32_16x16x32_bf16(rl1, qfh1, sacc[kt], 0, 0, 0);
            sacc[kt] = __builtin_amdgcn_mfma_f32_16x16x32_bf16(rh0, qfl0, sacc[kt], 0, 0, 0);
            sacc[kt] = __builtin_amdgcn_mfma_f32_16x16x32_bf16(rh1, qfl1, sacc[kt], 0, 0, 0);
        }
#pragma unroll
        for (int rd = 0; rd < 4; ++rd) {
            float bv = -3.0e38f; int bi = 0;
#pragma unroll
            for (int kp = 0; kp < 2; ++kp) {
#pragma unroll
                for (int rr = 0; rr < 4; ++rr) {
                    int i = kp * 16 + g * 4 + rr;
                    float v = sacc[rd * 2 + kp][rr];
                    if (v > bv) { bv = v; bi = i; }
                }
            }
#pragma unroll
            for (int kp = 0; kp < 2; ++kp) {
#pragma unroll
                for (int rr = 0; rr < 4; ++rr) {
                    int i = 32 + kp * 16 + g * 4 + rr;
                    float v = -sacc[rd * 2 + kp][rr];
                    if (v > bv) { bv = v; bi = i; }
                }
            }
#pragma unroll
            for (int dlt = 16; dlt <= 32; dlt <<= 1) {
                float ov = __shfl_xor(bv, dlt);
                int oi = __shfl_xor(bi, dlt);
                if (ov > bv || (ov == bv && oi < bi)) { bv = ov; bi = oi; }
            }
            if (g == 0)
                bkt[((size_t)(bh * NHASH_ + rd)) * T_ + tc * 128 + tl] = (unsigned char)bi;
        }
    }
}

// ---------------- parallel stable counting sort per (bh, round): 256 threads ----------------
__global__ __launch_bounds__(256) void k_sort(const unsigned char* __restrict__ bkt, int* __restrict__ st)
{
    __shared__ unsigned char bktL[T_];            // 4 KB
    __shared__ unsigned short hist[256][66];      // 33 KB, stride 66 breaks bank aliasing
    __shared__ unsigned short qtot[4][64];
    __shared__ int qbase[4][64];
    int tid = threadIdx.x;
    int bhr = blockIdx.x;
    const unsigned char* src = bkt + (size_t)bhr * T_;
    ((uint4*)bktL)[tid] = ((const uint4*)src)[tid];
    uint4* h4 = (uint4*)&hist[0][0];
    for (int j = tid; j < 2112; j += 256) h4[j] = make_uint4(0, 0, 0, 0);
    __syncthreads();
    int base = tid * 16;
#pragma unroll
    for (int i = 0; i < 16; ++i) hist[tid][bktL[base + i]]++;
    __syncthreads();
    int b = tid & 63, qd = tid >> 6;
    int t0 = qd * 64;
    unsigned run = 0;
#pragma unroll 8
    for (int tt = 0; tt < 64; ++tt) {
        unsigned v = hist[t0 + tt][b];
        hist[t0 + tt][b] = (unsigned short)run;
        run += v;
    }
    qtot[qd][b] = (unsigned short)run;
    __syncthreads();
    if (tid < 64) {
        int c0 = qtot[0][tid], c1 = qtot[1][tid], c2 = qtot[2][tid], c3 = qtot[3][tid];
        int tot = c0 + c1 + c2 + c3;
        int pre = tot;
#pragma unroll
        for (int d = 1; d < 64; d <<= 1) { int o = __shfl_up(pre, d); if (tid >= d) pre += o; }
        int startb = pre - tot;
        qbase[0][tid] = startb;
        qbase[1][tid] = startb + c0;
        qbase[2][tid] = startb + c0 + c1;
        qbase[3][tid] = startb + c0 + c1 + c2;
    }
    __syncthreads();
    int* dst = st + (size_t)bhr * T_;
#pragma unroll
    for (int i = 0; i < 16; ++i) {
        int bb = bktL[base + i];
        int off = hist[tid][bb]++;
        dst[qbase[qd][bb] + off] = base + i;
    }
}

// ---------------- MFMA chunked attention: one 4-wave block per (bh, chunk) ----------------
// o layout: [bh][t][rnd][64] bf16 ; lg layout: [bh][t][rnd] f32  (combine-coalesced)
// LDS 33.3KB: PbB aliases KbB (K dead after QK^T; barrier guards the overwrite) -> 4 blocks/CU.
__global__ __launch_bounds__(256, 4) void k_attn(const __hip_bfloat16* __restrict__ qh,
                                                 const __hip_bfloat16* __restrict__ kh,
                                                 const __hip_bfloat16* __restrict__ vh,
                                                 const int* __restrict__ st,
                                                 __hip_bfloat16* __restrict__ o,
                                                 float* __restrict__ lg)
{
    __shared__ __align__(16) char smem[33280];
    char* KbB = smem;                 // K tile (16KB); later aliased by PbB, then ObU
    char* VtB = smem + 16384;         // V^T tile (16KB)
    char* PbB = smem;                 // alias of KbB
    int*  kvt = (int*)(smem + 32768);
    unsigned short* ObU = (unsigned short*)smem;

    int tid = threadIdx.x;
    int lane = tid & 63;
    int g = lane >> 4;
    int wv = tid >> 6;
    int wq0 = wv * 16;

    int bid = blockIdx.x;
    int bh = ((bid & 7) << 1) | ((bid >> 3) & 1);
    int c  = bid >> 4;
    int rnd = c >> 6;
    int cp = (c + C_ - 1) & (C_ - 1);
    const size_t stB = (size_t)bh * NT_;

    if (tid < 128) {
        int cc = (tid < 64) ? c : cp;
        kvt[tid] = st[stB + (size_t)cc * 64 + (tid & 63)];
    }
    __syncthreads();

    {
        int k = tid >> 1, half = tid & 1;
        const uint4* src = (const uint4*)(kh + ((size_t)bh * T_ + kvt[k]) * 64 + half * 32);
#pragma unroll
        for (int j2 = 0; j2 < 4; ++j2) {
            uint4 a = src[j2];
            int blk = (half * 4 + j2) ^ (k & 7);
            *(uint4*)(KbB + k * 128 + blk * 16) = a;
        }
    }
    {
        int kp = tid & 63, dq = tid >> 6;
        const uint4* r0 = (const uint4*)(vh + ((size_t)bh * T_ + kvt[2 * kp]) * 64 + dq * 16);
        const uint4* r1 = (const uint4*)(vh + ((size_t)bh * T_ + kvt[2 * kp + 1]) * 64 + dq * 16);
        unsigned short va[16], vb2[16];
        *(uint4*)&va[0] = r0[0];  *(uint4*)&va[8] = r0[1];
        *(uint4*)&vb2[0] = r1[0]; *(uint4*)&vb2[8] = r1[1];
#pragma unroll
        for (int i = 0; i < 16; ++i) {
            int d = dq * 16 + i;
            unsigned wrd = (unsigned)va[i] | ((unsigned)vb2[i] << 16);
            *(unsigned*)(VtB + d * 256 + ((((kp >> 2) ^ i)) << 4) + ((kp & 3) << 2)) = wrd;
        }
    }
    int tq = kvt[wq0 + (lane & 15)];
    const __hip_bfloat16* qrow = qh + ((size_t)bh * T_ + tq) * 64;
    short8 qf0 = *(const short8*)(qrow + g * 8);
    short8 qf1 = *(const short8*)(qrow + 32 + g * 8);
    __syncthreads();

    f32x4 sacc[8];
#pragma unroll
    for (int kt = 0; kt < 8; ++kt) sacc[kt] = (f32x4){0.f, 0.f, 0.f, 0.f};
#pragma unroll
    for (int kt = 0; kt < 8; ++kt) {
        int row = kt * 16 + (lane & 15);
        short8 kf0 = *(const short8*)(KbB + row * 128 + (((g) ^ (row & 7)) << 4));
        short8 kf1 = *(const short8*)(KbB + row * 128 + (((4 + g) ^ (row & 7)) << 4));
        sacc[kt] = __builtin_amdgcn_mfma_f32_16x16x32_bf16(kf0, qf0, sacc[kt], 0, 0, 0);
        sacc[kt] = __builtin_amdgcn_mfma_f32_16x16x32_bf16(kf1, qf1, sacc[kt], 0, 0, 0);
    }

    float m = -3.0e38f;
#pragma unroll
    for (int kt = 0; kt < 8; ++kt) {
#pragma unroll
        for (int r = 0; r < 4; ++r) {
            int tk = kvt[kt * 16 + g * 4 + r];
            float dd = sacc[kt][r];
            dd = (tk > tq) ? MASKV : dd;
            dd = (tk == tq) ? SELFV : dd;
            sacc[kt][r] = dd;
            m = fmaxf(m, dd);
        }
    }
    m = fmaxf(m, __shfl_xor(m, 16));
    m = fmaxf(m, __shfl_xor(m, 32));
    __syncthreads();   // all KbB reads complete before P overwrites it (PbB alias)
    float ssum = 0.f;
#pragma unroll
    for (int kt = 0; kt < 8; ++kt) {
        float p0 = __expf(sacc[kt][0] - m);
        float p1 = __expf(sacc[kt][1] - m);
        float p2 = __expf(sacc[kt][2] - m);
        float p3 = __expf(sacc[kt][3] - m);
        ssum += (p0 + p1) + (p2 + p3);
        uint2 wrd = make_uint2(pk2(p0, p1), pk2(p2, p3));
        int blk = (kt * 2 + (g >> 1)) ^ (lane & 15);
        *(uint2*)(PbB + (wq0 + (lane & 15)) * 256 + (blk << 4) + ((g & 1) << 3)) = wrd;
    }
    ssum += __shfl_xor(ssum, 16);
    ssum += __shfl_xor(ssum, 32);
    if (lane < 16)
        lg[((size_t)bh * T_ + tq) * 4 + rnd] = m + __logf(ssum);

    f32x4 pacc[4];
#pragma unroll
    for (int dt = 0; dt < 4; ++dt) pacc[dt] = (f32x4){0.f, 0.f, 0.f, 0.f};
#pragma unroll
    for (int s = 0; s < 4; ++s) {
        int xr = ((s * 4 + g) ^ (lane & 15)) << 4;
        short8 pf = *(const short8*)(PbB + (wq0 + (lane & 15)) * 256 + xr);
#pragma unroll
        for (int dt = 0; dt < 4; ++dt) {
            short8 vf = *(const short8*)(VtB + (dt * 16 + (lane & 15)) * 256 + xr);
            pacc[dt] = __builtin_amdgcn_mfma_f32_16x16x32_bf16(pf, vf, pacc[dt], 0, 0, 0);
        }
    }
    __syncthreads();

#pragma unroll
    for (int r = 0; r < 4; ++r) {
        float sr = __shfl(ssum, g * 4 + r);
        float inv = 1.0f / sr;
        int rowl = wq0 + g * 4 + r;
#pragma unroll
        for (int dt = 0; dt < 4; ++dt) {
            __hip_bfloat16 hv = __float2bfloat16(pacc[dt][r] * inv);
            ObU[rowl * 72 + dt * 16 + (lane & 15)] = *(unsigned short*)&hv;
        }
    }
    __syncthreads();

    {
        int rr = tid >> 2, seg = tid & 3;
        uint4 a = *(const uint4*)(ObU + rr * 72 + seg * 16);
        uint4 b = *(const uint4*)(ObU + rr * 72 + seg * 16 + 8);
        size_t jor = (size_t)bh * T_ + kvt[rr];
        uint4* dst = (uint4*)(o + jor * 256 + rnd * 64 + seg * 16);
        dst[0] = a; dst[1] = b;
    }
}

// ---------------- combine hash rounds via softmax(logits) -> bf16 ----------------
// o layout: [bh][t][rnd][64] bf16 ; lg layout: [bh][t][rnd] f32
__global__ __launch_bounds__(256) void k_combine(const __hip_bfloat16* __restrict__ o,
                                                 const float* __restrict__ lg,
                                                 __hip_bfloat16* __restrict__ att)
{
    __shared__ float ws[H_][8];
    int bt = blockIdx.x;
    int bI = bt >> 12;
    int t  = bt & (T_ - 1);
    int tid = threadIdx.x;
    if (tid < H_) {
        size_t base = ((size_t)(bI * H_ + tid) * T_ + t);
        float4 L = *(const float4*)(lg + base * 4);
        float M = fmaxf(fmaxf(L.x, L.y), fmaxf(L.z, L.w));
        float w0 = __expf(L.x - M), w1 = __expf(L.y - M), w2 = __expf(L.z - M), w3 = __expf(L.w - M);
        float inv = 1.0f / (w0 + w1 + w2 + w3);
        ws[tid][0] = w0 * inv; ws[tid][1] = w1 * inv; ws[tid][2] = w2 * inv; ws[tid][3] = w3 * inv;
    }
    __syncthreads();
#pragma unroll
    for (int it = 0; it < 2; ++it) {
        int e = it * 256 + tid;
        int h = e >> 6, f = e & 63;
        const __hip_bfloat16* op = o + ((size_t)(bI * H_ + h) * T_ + t) * 256;
        float val = __bfloat162float(op[f])       * ws[h][0]
                  + __bfloat162float(op[64 + f])  * ws[h][1]
                  + __bfloat162float(op[128 + f]) * ws[h][2]
                  + __bfloat162float(op[192 + f]) * ws[h][3];
        att[(size_t)bt * E_ + e] = __float2bfloat16(val);
    }
}

// ---------------- pooling + final linear ----------------
__global__ __launch_bounds__(256) void k_pool1(const float* __restrict__ x1, const float* __restrict__ x2,
                                               float* __restrict__ part)
{
    int blk = blockIdx.x;
    int bI = blk >> 5, tc = blk & 31;
    int t0 = tc * 128;
    for (int e = threadIdx.x; e < E_; e += 256) {
        float s = 0.f;
        for (int t = t0; t < t0 + 128; ++t) {
            size_t idx = ((size_t)bI * T_ + t) * E_ + e;
            s += x1[idx] + x2[idx];
        }
        part[((size_t)bI * 32 + tc) * E_ + e] = s;
    }
}

__global__ __launch_bounds__(256) void k_final(const float* __restrict__ part, const float* __restrict__ wf,
                                               const float* __restrict__ bf, float* __restrict__ out)
{
    __shared__ float pooled[B_ * E_];
    int tid = threadIdx.x;
    for (int i = tid; i < B_ * E_; i += 256) {
        int bI = i >> 9, e = i & 511;
        float s = 0.f;
        for (int c2 = 0; c2 < 32; ++c2) s += part[((size_t)bI * 32 + c2) * E_ + e];
        pooled[i] = s * (0.5f / T_);
    }
    __syncthreads();
    if (tid < B_ * NCLASS_) {
        int bI = tid / NCLASS_, cl = tid % NCLASS_;
        float s = bf[cl];
        for (int e = 0; e < E_; ++e) s += pooled[bI * E_ + e] * wf[(size_t)e * NCLASS_ + cl];
        out[tid] = s;
    }
}

// ---------------- orchestration ----------------
extern "C" void kernel_launch(void* const* d_in, const int* in_sizes, int n_in,
                              void* d_out, int out_size, void* d_ws, size_t ws_size,
                              hipStream_t stream)
{
    const int*   X    = (const int*)d_in[0];
    const float* TOK  = (const float*)d_in[1];
    const float* POS  = (const float*)d_in[2];
    const float* ROT  = (const float*)d_in[3];
    const float* LN1G = (const float*)d_in[4];
    const float* LN1B = (const float*)d_in[5];
    const float* WQK  = (const float*)d_in[6];
    const float* WV   = (const float*)d_in[7];
    const float* WO   = (const float*)d_in[8];
    const float* BO   = (const float*)d_in[9];
    const float* LN2G = (const float*)d_in[10];
    const float* LN2B = (const float*)d_in[11];
    const float* WF1  = (const float*)d_in[12];
    const float* BF1  = (const float*)d_in[13];
    const float* WF2  = (const float*)d_in[14];
    const float* BF2  = (const float*)d_in[15];
    const float* WFIN = (const float*)d_in[16];
    const float* BFIN = (const float*)d_in[17];

    float* ws = (float*)d_ws;
    const size_t S = (size_t)B_ * T_ * E_;
    float* x1   = ws;
    float* x2   = x1 + S;
    float* qkb  = x2 + S;
    float* vb   = qkb + S;                 // unused (kept for layout stability)
    float* bigf = vb + S;
    float* lgb  = bigf + 2 * S;
    float* part = lgb + (size_t)BH_ * NT_;
    __hip_bfloat16* lnbh  = (__hip_bfloat16*)(part + (size_t)B_ * 32 * E_);
    __hip_bfloat16* lnbl  = lnbh + S;
    __hip_bfloat16* attnb = lnbl + S;
    int*   stb  = (int*)(attnb + S);
    __hip_bfloat16* WTbase = (__hip_bfloat16*)(stb + (size_t)BH_ * NT_);
    __hip_bfloat16* big    = (__hip_bfloat16*)bigf;

    const size_t W55 = (size_t)512 * 512;
    const size_t WFF = (size_t)2048 * 512;
    __hip_bfloat16* WTqk_hi = WTbase;
    __hip_bfloat16* WTqk_lo = WTqk_hi + 4 * W55;
    __hip_bfloat16* WTv     = WTqk_lo + 4 * W55;
    __hip_bfloat16* WTo     = WTv     + 4 * W55;
    __hip_bfloat16* WTf1    = WTo     + 4 * W55;
    __hip_bfloat16* WTf2    = WTf1    + 4 * WFF;
    unsigned char*  bktb    = (unsigned char*)(WTf2 + 4 * WFF);
    __hip_bfloat16* qh      = (__hip_bfloat16*)(bktb + (size_t)BH_ * NHASH_ * T_);
    __hip_bfloat16* khb     = qh  + (size_t)BH_ * T_ * 64;
    __hip_bfloat16* vhb     = khb + (size_t)BH_ * T_ * 64;
    __hip_bfloat16* rswzh   = vhb + (size_t)BH_ * T_ * 64;   // 4 layers x 8192 bf16
    __hip_bfloat16* rswzl   = rswzh + 4 * 8192;

    // batched weight prep: layer dim in blockIdx.z / blockIdx.x (24 launches -> 6)
    k_wprep<true ><<<dim3(16, 16, 4), 256, 0, stream>>>(WQK, WTqk_hi, WTqk_lo, 512, 512);
    k_wprep<false><<<dim3(16, 16, 4), 256, 0, stream>>>(WV, WTv, nullptr, 512, 512);
    k_wprep<false><<<dim3(16, 16, 4), 256, 0, stream>>>(WO, WTo, nullptr, 512, 512);
    k_wprep<false><<<dim3(64, 16, 4), 256, 0, stream>>>(WF1, WTf1, nullptr, 512, 2048);
    k_wprep<false><<<dim3(16, 64, 4), 256, 0, stream>>>(WF2, WTf2, nullptr, 2048, 512);
    k_rotprep<<<4, 256, 0, stream>>>(ROT, rswzh, rswzl);

    const int g512_64 = (512 / 128) * ((B_ * T_) / 64);   // 512 blocks (TM=64)
    const int gqk     = ((B_ * T_) / 64) * (512 / 64);    // 1024 blocks (64x64 QK)
    const int gff1    = ((B_ * T_) / 256) * (FF_ / 256);  // 256 blocks (256^2 8-phase FF1)

    k_embed<<<B_ * T_, 128, 0, stream>>>(X, TOK, POS, x1, x2);
    for (int d = 0; d < DEPTH_; ++d) {
        // --- attention half: x1 += attn(ln1(x2)) ---
        k_ln<true><<<B_ * T_, 128, 0, stream>>>(x2, LN1G + (size_t)d * E_, LN1B + (size_t)d * E_, lnbh, lnbl);
        k_qk64<<<gqk, 256, 0, stream>>>(lnbh, lnbl, WTqk_hi + d * W55, WTqk_lo + d * W55, qkb);
        k_mgemm<3, 0, 64><<<g512_64, 256, 0, stream>>>(lnbh, WTv + d * W55, nullptr, vhb, 512, 512, 2);
        k_hash<<<dim3(BH_, T_ / 128), 256, 0, stream>>>(qkb, rswzh + d * 8192, rswzl + d * 8192,
                                                        bktb, qh, khb);
        k_sort<<<BH_ * NHASH_, 256, 0, stream>>>(bktb, stb);
        k_attn<<<BH_ * C_, 256, 0, stream>>>(qh, khb, vhb, stb, big, lgb);
        k_combine<<<B_ * T_, 256, 0, stream>>>(big, lgb, attnb);
        k_mgemm<1, 1, 64><<<g512_64, 256, 0, stream>>>(attnb, WTo + d * W55, BO + (size_t)d * E_, x1,
                                                       512, 512, 2);
        // --- ff half: x2 += ff(ln2(x1)) ---
        k_ln<false><<<B_ * T_, 128, 0, stream>>>(x1, LN2G + (size_t)d * E_, LN2B + (size_t)d * E_, lnbh, nullptr);
        k_gemm256_gelu<<<gff1, 512, 0, stream>>>(lnbh, WTf1 + d * WFF, BF1 + (size_t)d * FF_, big,
                                                 2048, 512, 3);
        k_mgemm<1, 1, 64><<<g512_64, 256, 0, stream>>>(big, WTf2 + d * WFF, BF2 + (size_t)d * E_, x2,
                                                       512, 2048, 2);
    }
    k_pool1<<<B_ * 32, 256, 0, stream>>>(x1, x2, part);
    k_final<<<1, 256, 0, stream>>>(part, WFIN, BFIN, (float*)d_out);
}